// Round 1
// baseline (808.982 us; speedup 1.0000x reference)
//
#include <hip/hip_runtime.h>

#define NA      30000
#define NPAIRS  1200000
#define NB      7
#define NK      5
#define NSP     119
#define NFEAT   360
#define NU      512

// constants (match reference, computed in double then rounded)
#define BETTA      1.3611111111111112f     // 49/36
#define RADNORM    0.96481348f             // (2*betta/pi)^0.25
#define SHIFT_STEP 0.7857142857142857f     // 5.5/7
#define PI_OVER_R  0.5235987755982988f     // pi/6
#define INV_SQRT7  0.3779644730092272f
#define RMAXV      6.0f

// ---------------- CSR build ----------------
__global__ void k_count(const int* __restrict__ idx, int* __restrict__ counts) {
    int p = blockIdx.x * blockDim.x + threadIdx.x;
    if (p < NPAIRS) atomicAdd(&counts[idx[p]], 1);
}

__global__ void k_offsets(const int* __restrict__ counts, int* __restrict__ startp,
                          int* __restrict__ wcur, int* __restrict__ cursor) {
    int a = blockIdx.x * blockDim.x + threadIdx.x;
    if (a < NA) {
        int c = counts[a];
        int s = atomicAdd(cursor, c);   // segment placement order is irrelevant
        startp[a] = s;
        wcur[a] = s;
    }
}

__global__ void k_fill(const int* __restrict__ idx, const int* __restrict__ Z,
                       int* __restrict__ wcur, int* __restrict__ plist) {
    int p = blockIdx.x * blockDim.x + threadIdx.x;
    if (p < NPAIRS) {
        int i = idx[p];
        int j = idx[NPAIRS + p];
        int pos = atomicAdd(&wcur[i], 1);
        plist[pos] = j | (Z[j] << 20);   // pack neighbor idx + species
    }
}

// ---------------- moments (segment-summed, unique symmetric comps) ----------------
// MT layout: [5 k][20 u] transposed -> MT[(k*20+u)*NA + a]
// u: 0=1, 1..3=dn, 4..9 = xx,xy,xz,yy,yz,zz, 10..19 = xxx,xxy,xxz,xyy,xyz,xzz,yyy,yyz,yzz,zzz
__global__ void k_moments(const float* __restrict__ R, const int* __restrict__ Z,
                          const float* __restrict__ W,
                          const int* __restrict__ startp, const int* __restrict__ counts,
                          const int* __restrict__ plist, float* __restrict__ MT) {
    int a = blockIdx.x * blockDim.x + threadIdx.x;
    if (a >= NA) return;
    float Rx = R[3*a], Ry = R[3*a+1], Rz = R[3*a+2];
    int Zi = Z[a];
    float acc[100];
#pragma unroll
    for (int u = 0; u < 100; u++) acc[u] = 0.f;
    int cnt = counts[a], base = startp[a];
    for (int t = 0; t < cnt; t++) {
        int pk = plist[base + t];
        int j  = pk & 0xFFFFF;
        int Zj = pk >> 20;
        float dx = R[3*j]   - Rx;
        float dy = R[3*j+1] - Ry;
        float dz = R[3*j+2] - Rz;
        float d2 = dx*dx + dy*dy + dz*dz + 1e-12f;
        float dr = sqrtf(d2);
        float inv = 1.0f / (dr + 1e-5f);
        float nx = dx*inv, ny = dy*inv, nz = dz*inv;
        float basis[NB];
#pragma unroll
        for (int b = 0; b < NB; b++) {
            float tt = dr - (0.5f + SHIFT_STEP * (float)b);
            basis[b] = RADNORM * __expf(-BETTA * tt * tt);
        }
        float cut = (dr < RMAXV) ? 0.5f * (__cosf(PI_OVER_R * dr) + 1.0f) : 0.0f;
        cut *= INV_SQRT7;
        const float* cw = W + ((Zi * NSP + Zj) * (NK * NB));
        float rad[NK];
#pragma unroll
        for (int k = 0; k < NK; k++) {
            float s = 0.f;
#pragma unroll
            for (int b = 0; b < NB; b++) s += cw[k*NB + b] * basis[b];
            rad[k] = s * cut;
        }
        float g[20];
        g[0] = 1.f; g[1] = nx; g[2] = ny; g[3] = nz;
        g[4] = nx*nx; g[5] = nx*ny; g[6] = nx*nz; g[7] = ny*ny; g[8] = ny*nz; g[9] = nz*nz;
        g[10] = g[4]*nx; g[11] = g[4]*ny; g[12] = g[4]*nz; g[13] = g[5]*ny; g[14] = g[5]*nz;
        g[15] = g[6]*nz; g[16] = g[7]*ny; g[17] = g[7]*nz; g[18] = g[8]*nz; g[19] = g[9]*nz;
#pragma unroll
        for (int k = 0; k < NK; k++)
#pragma unroll
            for (int u = 0; u < 20; u++)
                acc[k*20 + u] += rad[k] * g[u];
    }
#pragma unroll
    for (int u = 0; u < 100; u++) MT[u * NA + a] = acc[u];
}

// ---------------- contractions -> gmT [360][NA] ----------------
__global__ void k_contract(const float* __restrict__ MT, float* __restrict__ gmT) {
    int a = blockIdx.x * blockDim.x + threadIdx.x;
    if (a >= NA) return;
    float m0v[5], m1v[5][3], m2s[5][6], m3s[5][10];
#pragma unroll
    for (int k = 0; k < 5; k++) {
        m0v[k] = MT[(k*20 + 0)*NA + a];
#pragma unroll
        for (int i = 0; i < 3; i++)  m1v[k][i] = MT[(k*20 + 1 + i)*NA + a];
#pragma unroll
        for (int u = 0; u < 6; u++)  m2s[k][u] = MT[(k*20 + 4 + u)*NA + a];
#pragma unroll
        for (int u = 0; u < 10; u++) m3s[k][u] = MT[(k*20 + 10 + u)*NA + a];
    }
    const int S2[3][3] = {{0,1,2},{1,3,4},{2,4,5}};
    const int S3[3][3][3] = {
        {{0,1,2},{1,3,4},{2,4,5}},
        {{1,3,4},{3,6,7},{4,7,8}},
        {{2,4,5},{4,7,8},{5,8,9}}
    };
    const float W2U[6]  = {1,2,2,1,2,1};
    const float W3U[10] = {1,3,3,3,6,3,1,3,3,1};
    int f = 0;
    // m0
#pragma unroll
    for (int k = 0; k < 5; k++) gmT[(f++)*NA + a] = m0v[k];
    // c1 (tri2)
#pragma unroll
    for (int r = 0; r < 5; r++)
#pragma unroll
        for (int s = r; s < 5; s++) {
            float v = 0.f;
#pragma unroll
            for (int i = 0; i < 3; i++) v += m1v[r][i] * m1v[s][i];
            gmT[(f++)*NA + a] = v;
        }
    // c2 (tri2, weighted unique)
#pragma unroll
    for (int r = 0; r < 5; r++)
#pragma unroll
        for (int s = r; s < 5; s++) {
            float v = 0.f;
#pragma unroll
            for (int u = 0; u < 6; u++) v += W2U[u] * m2s[r][u] * m2s[s][u];
            gmT[(f++)*NA + a] = v;
        }
    // c3 (tri2, weighted unique)
#pragma unroll
    for (int r = 0; r < 5; r++)
#pragma unroll
        for (int s = r; s < 5; s++) {
            float v = 0.f;
#pragma unroll
            for (int u = 0; u < 10; u++) v += W3U[u] * m3s[r][u] * m3s[s][u];
            gmT[(f++)*NA + a] = v;
        }
    // c4 (tri3)
#pragma unroll
    for (int r = 0; r < 5; r++)
#pragma unroll
        for (int s = r; s < 5; s++)
#pragma unroll
            for (int t = s; t < 5; t++) {
                float v = 0.f;
#pragma unroll
                for (int i = 0; i < 3; i++)
#pragma unroll
                    for (int j = 0; j < 3; j++)
#pragma unroll
                        for (int k = 0; k < 3; k++)
                            v += m2s[r][S2[i][j]] * m2s[s][S2[i][k]] * m2s[t][S2[j][k]];
                gmT[(f++)*NA + a] = v;
            }
    // c5 (tri2 over r,s  x all t)
#pragma unroll
    for (int r = 0; r < 5; r++)
#pragma unroll
        for (int s = r; s < 5; s++)
#pragma unroll
            for (int t = 0; t < 5; t++) {
                float v = 0.f;
#pragma unroll
                for (int i = 0; i < 3; i++)
#pragma unroll
                    for (int j = 0; j < 3; j++)
                        v += m1v[r][i] * m1v[s][j] * m2s[t][S2[i][j]];
                gmT[(f++)*NA + a] = v;
            }
    // c6 (tri2 over r,s x all t)
#pragma unroll
    for (int r = 0; r < 5; r++)
#pragma unroll
        for (int s = r; s < 5; s++) {
            float T[3][3];
#pragma unroll
            for (int k = 0; k < 3; k++)
#pragma unroll
                for (int l = 0; l < 3; l++) {
                    float v = 0.f;
#pragma unroll
                    for (int i = 0; i < 3; i++)
#pragma unroll
                        for (int j = 0; j < 3; j++)
                            v += m3s[r][S3[i][j][k]] * m3s[s][S3[i][j][l]];
                    T[k][l] = v;
                }
#pragma unroll
            for (int t = 0; t < 5; t++) {
                float v = 0.f;
#pragma unroll
                for (int k = 0; k < 3; k++)
#pragma unroll
                    for (int l = 0; l < 3; l++)
                        v += T[k][l] * m2s[t][S2[k][l]];
                gmT[(f++)*NA + a] = v;
            }
        }
    // c7 (full r,s,t)
#pragma unroll
    for (int r = 0; r < 5; r++)
#pragma unroll
        for (int s = 0; s < 5; s++) {
            float U[3];
#pragma unroll
            for (int k = 0; k < 3; k++) {
                float v = 0.f;
#pragma unroll
                for (int i = 0; i < 3; i++)
#pragma unroll
                    for (int j = 0; j < 3; j++)
                        v += m3s[r][S3[i][j][k]] * m2s[s][S2[i][j]];
                U[k] = v;
            }
#pragma unroll
            for (int t = 0; t < 5; t++) {
                float v = U[0]*m1v[t][0] + U[1]*m1v[t][1] + U[2]*m1v[t][2];
                gmT[(f++)*NA + a] = v;
            }
        }
}

// ---------------- fp32 tiled GEMM with fused bias+swish ----------------
// X: [K][NA] (transposed activations), W: [K][C], O: [C][NA]
#define TILE 64
#define KT   16
__global__ __launch_bounds__(256) void k_gemm(const float* __restrict__ X,
                                              const float* __restrict__ W,
                                              const float* __restrict__ bias,
                                              float* __restrict__ O,
                                              int K, int C) {
    __shared__ float Xs[KT][TILE];
    __shared__ float Ws[KT][TILE];
    int tid = threadIdx.x;
    int tx = tid & 15;        // atom sub-tile
    int ty = tid >> 4;        // col sub-tile
    int aBase = blockIdx.x * TILE;
    int cBase = blockIdx.y * TILE;
    float acc[4][4];
#pragma unroll
    for (int i = 0; i < 4; i++)
#pragma unroll
        for (int j = 0; j < 4; j++) acc[i][j] = 0.f;

    int lk = tid >> 4;          // 0..15 : k row to load
    int la = (tid & 15) * 4;    // 0..60 : 4-float column chunk

    for (int k0 = 0; k0 < K; k0 += KT) {
        int kg = k0 + lk;
        float4 xv = make_float4(0.f, 0.f, 0.f, 0.f);
        float4 wv = make_float4(0.f, 0.f, 0.f, 0.f);
        if (kg < K) {
            int ac = aBase + la;
            if (ac < NA) xv = *(const float4*)&X[kg * NA + ac];
            wv = *(const float4*)&W[kg * C + cBase + la];
        }
        *(float4*)&Xs[lk][la] = xv;
        *(float4*)&Ws[lk][la] = wv;
        __syncthreads();
#pragma unroll
        for (int kk = 0; kk < KT; kk++) {
            float4 xa = *(const float4*)&Xs[kk][tx * 4];
            float4 wb = *(const float4*)&Ws[kk][ty * 4];
            float xr[4] = {xa.x, xa.y, xa.z, xa.w};
            float wr[4] = {wb.x, wb.y, wb.z, wb.w};
#pragma unroll
            for (int cc = 0; cc < 4; cc++)
#pragma unroll
                for (int ai = 0; ai < 4; ai++)
                    acc[cc][ai] += wr[cc] * xr[ai];
        }
        __syncthreads();
    }
    int aa = aBase + tx * 4;
    if (aa < NA) {
#pragma unroll
        for (int cc = 0; cc < 4; cc++) {
            int c = cBase + ty * 4 + cc;
            float b = bias[c];
            float4 o;
            float v;
            v = acc[cc][0] + b; o.x = v / (1.f + __expf(-v));
            v = acc[cc][1] + b; o.y = v / (1.f + __expf(-v));
            v = acc[cc][2] + b; o.z = v / (1.f + __expf(-v));
            v = acc[cc][3] + b; o.w = v / (1.f + __expf(-v));
            *(float4*)&O[c * NA + aa] = o;
        }
    }
}

// ---------------- final layer + per-species scale/shift ----------------
__global__ void k_final(const float* __restrict__ h2T, const float* __restrict__ w3,
                        const float* __restrict__ b3, const int* __restrict__ Z,
                        const float* __restrict__ scale, const float* __restrict__ shift,
                        float* __restrict__ out) {
    int a = blockIdx.x * blockDim.x + threadIdx.x;
    if (a >= NA) return;
    float s = 0.f;
#pragma unroll 8
    for (int c = 0; c < NU; c++) s += w3[c] * h2T[c * NA + a];
    s += b3[0];
    int z = Z[a];
    out[a] = scale[z] * s + shift[z];
}

extern "C" void kernel_launch(void* const* d_in, const int* in_sizes, int n_in,
                              void* d_out, int out_size, void* d_ws, size_t ws_size,
                              hipStream_t stream) {
    const float* R    = (const float*)d_in[0];
    const int*   Z    = (const int*)  d_in[1];
    const int*   idx  = (const int*)  d_in[2];
    const float* Wr   = (const float*)d_in[3];
    const float* w1   = (const float*)d_in[4];
    const float* b1   = (const float*)d_in[5];
    const float* w2   = (const float*)d_in[6];
    const float* b2   = (const float*)d_in[7];
    const float* w3   = (const float*)d_in[8];
    const float* b3   = (const float*)d_in[9];
    const float* scale= (const float*)d_in[10];
    const float* shift= (const float*)d_in[11];
    float* out = (float*)d_out;
    char* ws = (char*)d_ws;

    // workspace layout (bytes)
    int*   counts = (int*)  (ws + 0);          // 120000
    int*   cursor = (int*)  (ws + 120000);     // 4
    int*   startp = (int*)  (ws + 120064);     // 120000
    int*   wcur   = (int*)  (ws + 240128);     // 120000
    int*   plist  = (int*)  (ws + 360192);     // 4800000
    float* MT     = (float*)(ws + 5160448);    // 12000000
    float* gmT    = (float*)(ws + 17160448);   // 43200000
    float* h1T    = (float*)(ws + 60360448);   // 61440000
    float* h2T    = (float*)(ws + 121800448);  // 61440000  (end 183240448)

    hipMemsetAsync(counts, 0, 120004, stream);  // counts + cursor

    k_count  <<<(NPAIRS + 255) / 256, 256, 0, stream>>>(idx, counts);
    k_offsets<<<(NA + 255) / 256,     256, 0, stream>>>(counts, startp, wcur, cursor);
    k_fill   <<<(NPAIRS + 255) / 256, 256, 0, stream>>>(idx, Z, wcur, plist);
    k_moments<<<(NA + 127) / 128,     128, 0, stream>>>(R, Z, Wr, startp, counts, plist, MT);
    k_contract<<<(NA + 127) / 128,    128, 0, stream>>>(MT, gmT);

    dim3 g1((NA + TILE - 1) / TILE, NU / TILE);
    k_gemm<<<g1, 256, 0, stream>>>(gmT, w1, b1, h1T, NFEAT, NU);
    k_gemm<<<g1, 256, 0, stream>>>(h1T, w2, b2, h2T, NU, NU);

    k_final<<<(NA + 255) / 256, 256, 0, stream>>>(h2T, w3, b3, Z, scale, shift, out);
}

// Round 2
// 619.456 us; speedup vs baseline: 1.3060x; 1.3060x over previous
//
#include <hip/hip_runtime.h>

#define NA      30000
#define MPAD    30080            // 235 * 128
#define NPAIRS  1200000
#define NB      7
#define NK      5
#define NSP     119
#define NFEAT   360
#define KP1     384              // NFEAT padded to 64
#define NU      512

#define BETTA      1.3611111111111112f     // 49/36
#define RADNORM    0.96481348f             // (2*betta/pi)^0.25
#define SHIFT_STEP 0.7857142857142857f     // 5.5/7
#define PI_OVER_R  0.5235987755982988f     // pi/6
#define INV_SQRT7  0.3779644730092272f
#define RMAXV      6.0f

typedef __attribute__((ext_vector_type(8))) short bf16x8;
typedef __attribute__((ext_vector_type(4))) float f32x4;

__device__ __forceinline__ unsigned short f2b(float x) {
    unsigned u = __float_as_uint(x);
    unsigned r = u + 0x7FFF + ((u >> 16) & 1);   // RNE (inputs are finite)
    return (unsigned short)(r >> 16);
}

// ---------------- CSR build ----------------
__global__ void k_count(const int* __restrict__ idx, int* __restrict__ counts) {
    int p = blockIdx.x * blockDim.x + threadIdx.x;
    if (p < NPAIRS) atomicAdd(&counts[idx[p]], 1);
}

__global__ void k_offsets(const int* __restrict__ counts, int* __restrict__ startp,
                          int* __restrict__ wcur, int* __restrict__ cursor) {
    int a = blockIdx.x * blockDim.x + threadIdx.x;
    if (a < NA) {
        int c = counts[a];
        int s = atomicAdd(cursor, c);
        startp[a] = s;
        wcur[a] = s;
    }
}

__global__ void k_fill(const int* __restrict__ idx, const int* __restrict__ Z,
                       int* __restrict__ wcur, int* __restrict__ plist) {
    int p = blockIdx.x * blockDim.x + threadIdx.x;
    if (p < NPAIRS) {
        int i = idx[p];
        int j = idx[NPAIRS + p];
        int pos = atomicAdd(&wcur[i], 1);
        plist[pos] = j | (Z[j] << 20);
    }
}

// ---------------- moments: 4 threads per atom, shuffle-reduced ----------------
// MT layout: [100][NA], u: 0=1, 1..3=n, 4..9=xx,xy,xz,yy,yz,zz, 10..19=3rd order
__global__ void k_moments(const float* __restrict__ R, const int* __restrict__ Z,
                          const float* __restrict__ W,
                          const int* __restrict__ startp, const int* __restrict__ counts,
                          const int* __restrict__ plist, float* __restrict__ MT) {
    int tid = blockIdx.x * blockDim.x + threadIdx.x;
    int a = tid >> 2, q = tid & 3;
    if (a >= NA) return;
    float Rx = R[3*a], Ry = R[3*a+1], Rz = R[3*a+2];
    int Zi = Z[a];
    float acc[100];
#pragma unroll
    for (int u = 0; u < 100; u++) acc[u] = 0.f;
    int cnt = counts[a], base = startp[a];
    for (int t = q; t < cnt; t += 4) {
        int pk = plist[base + t];
        int j  = pk & 0xFFFFF;
        int Zj = pk >> 20;
        float dx = R[3*j]   - Rx;
        float dy = R[3*j+1] - Ry;
        float dz = R[3*j+2] - Rz;
        float d2 = dx*dx + dy*dy + dz*dz + 1e-12f;
        float dr = sqrtf(d2);
        float inv = 1.0f / (dr + 1e-5f);
        float nx = dx*inv, ny = dy*inv, nz = dz*inv;
        float basis[NB];
#pragma unroll
        for (int b = 0; b < NB; b++) {
            float tt = dr - (0.5f + SHIFT_STEP * (float)b);
            basis[b] = RADNORM * __expf(-BETTA * tt * tt);
        }
        float cut = (dr < RMAXV) ? 0.5f * (__cosf(PI_OVER_R * dr) + 1.0f) : 0.0f;
        cut *= INV_SQRT7;
        const float* cw = W + ((Zi * NSP + Zj) * (NK * NB));
        float rad[NK];
#pragma unroll
        for (int k = 0; k < NK; k++) {
            float s = 0.f;
#pragma unroll
            for (int b = 0; b < NB; b++) s += cw[k*NB + b] * basis[b];
            rad[k] = s * cut;
        }
        float g[20];
        g[0] = 1.f; g[1] = nx; g[2] = ny; g[3] = nz;
        g[4] = nx*nx; g[5] = nx*ny; g[6] = nx*nz; g[7] = ny*ny; g[8] = ny*nz; g[9] = nz*nz;
        g[10] = g[4]*nx; g[11] = g[4]*ny; g[12] = g[4]*nz; g[13] = g[5]*ny; g[14] = g[5]*nz;
        g[15] = g[6]*nz; g[16] = g[7]*ny; g[17] = g[7]*nz; g[18] = g[8]*nz; g[19] = g[9]*nz;
#pragma unroll
        for (int k = 0; k < NK; k++)
#pragma unroll
            for (int u = 0; u < 20; u++)
                acc[k*20 + u] += rad[k] * g[u];
    }
#pragma unroll
    for (int u = 0; u < 100; u++) {
        float v = acc[u];
        v += __shfl_xor(v, 1);
        v += __shfl_xor(v, 2);
        acc[u] = v;
    }
    if (q == 0) {
#pragma unroll
        for (int u = 0; u < 100; u++) MT[u * NA + a] = acc[u];
    }
}

// ---------------- contractions -> gmB [MPAD][KP1] bf16 (atom-major, zero-padded) ----
__global__ void k_contract(const float* __restrict__ MT, unsigned short* __restrict__ gmB) {
    int a = blockIdx.x * blockDim.x + threadIdx.x;
    if (a >= NA) return;
    float m0v[5], m1v[5][3], m2s[5][6], m3s[5][10];
#pragma unroll
    for (int k = 0; k < 5; k++) {
        m0v[k] = MT[(k*20 + 0)*NA + a];
#pragma unroll
        for (int i = 0; i < 3; i++)  m1v[k][i] = MT[(k*20 + 1 + i)*NA + a];
#pragma unroll
        for (int u = 0; u < 6; u++)  m2s[k][u] = MT[(k*20 + 4 + u)*NA + a];
#pragma unroll
        for (int u = 0; u < 10; u++) m3s[k][u] = MT[(k*20 + 10 + u)*NA + a];
    }
    const int S2[3][3] = {{0,1,2},{1,3,4},{2,4,5}};
    const int S3[3][3][3] = {
        {{0,1,2},{1,3,4},{2,4,5}},
        {{1,3,4},{3,6,7},{4,7,8}},
        {{2,4,5},{4,7,8},{5,8,9}}
    };
    const float W2U[6]  = {1,2,2,1,2,1};
    const float W3U[10] = {1,3,3,3,6,3,1,3,3,1};
    unsigned short* row = gmB + (size_t)a * KP1;
    int f = 0;
#pragma unroll
    for (int k = 0; k < 5; k++) row[f++] = f2b(m0v[k]);
#pragma unroll
    for (int r = 0; r < 5; r++)
#pragma unroll
        for (int s = r; s < 5; s++) {
            float v = 0.f;
#pragma unroll
            for (int i = 0; i < 3; i++) v += m1v[r][i] * m1v[s][i];
            row[f++] = f2b(v);
        }
#pragma unroll
    for (int r = 0; r < 5; r++)
#pragma unroll
        for (int s = r; s < 5; s++) {
            float v = 0.f;
#pragma unroll
            for (int u = 0; u < 6; u++) v += W2U[u] * m2s[r][u] * m2s[s][u];
            row[f++] = f2b(v);
        }
#pragma unroll
    for (int r = 0; r < 5; r++)
#pragma unroll
        for (int s = r; s < 5; s++) {
            float v = 0.f;
#pragma unroll
            for (int u = 0; u < 10; u++) v += W3U[u] * m3s[r][u] * m3s[s][u];
            row[f++] = f2b(v);
        }
#pragma unroll
    for (int r = 0; r < 5; r++)
#pragma unroll
        for (int s = r; s < 5; s++)
#pragma unroll
            for (int t = s; t < 5; t++) {
                float v = 0.f;
#pragma unroll
                for (int i = 0; i < 3; i++)
#pragma unroll
                    for (int j = 0; j < 3; j++)
#pragma unroll
                        for (int k = 0; k < 3; k++)
                            v += m2s[r][S2[i][j]] * m2s[s][S2[i][k]] * m2s[t][S2[j][k]];
                row[f++] = f2b(v);
            }
#pragma unroll
    for (int r = 0; r < 5; r++)
#pragma unroll
        for (int s = r; s < 5; s++)
#pragma unroll
            for (int t = 0; t < 5; t++) {
                float v = 0.f;
#pragma unroll
                for (int i = 0; i < 3; i++)
#pragma unroll
                    for (int j = 0; j < 3; j++)
                        v += m1v[r][i] * m1v[s][j] * m2s[t][S2[i][j]];
                row[f++] = f2b(v);
            }
#pragma unroll
    for (int r = 0; r < 5; r++)
#pragma unroll
        for (int s = r; s < 5; s++) {
            float T[3][3];
#pragma unroll
            for (int k = 0; k < 3; k++)
#pragma unroll
                for (int l = 0; l < 3; l++) {
                    float v = 0.f;
#pragma unroll
                    for (int i = 0; i < 3; i++)
#pragma unroll
                        for (int j = 0; j < 3; j++)
                            v += m3s[r][S3[i][j][k]] * m3s[s][S3[i][j][l]];
                    T[k][l] = v;
                }
#pragma unroll
            for (int t = 0; t < 5; t++) {
                float v = 0.f;
#pragma unroll
                for (int k = 0; k < 3; k++)
#pragma unroll
                    for (int l = 0; l < 3; l++)
                        v += T[k][l] * m2s[t][S2[k][l]];
                row[f++] = f2b(v);
            }
        }
#pragma unroll
    for (int r = 0; r < 5; r++)
#pragma unroll
        for (int s = 0; s < 5; s++) {
            float U[3];
#pragma unroll
            for (int k = 0; k < 3; k++) {
                float v = 0.f;
#pragma unroll
                for (int i = 0; i < 3; i++)
#pragma unroll
                    for (int j = 0; j < 3; j++)
                        v += m3s[r][S3[i][j][k]] * m2s[s][S2[i][j]];
                U[k] = v;
            }
#pragma unroll
            for (int t = 0; t < 5; t++)
                row[f++] = f2b(U[0]*m1v[t][0] + U[1]*m1v[t][1] + U[2]*m1v[t][2]);
        }
    // zero-pad K to 384
#pragma unroll
    for (int z = NFEAT; z < KP1; z++) row[z] = 0;
}

// ---------------- weight transpose+cast: w[K][512] -> wt[512][KPad] bf16, zero-padded
__global__ void k_wt(const float* __restrict__ w, unsigned short* __restrict__ wt,
                     int K, int KPad) {
    int i = blockIdx.x * blockDim.x + threadIdx.x;
    if (i >= NU * KPad) return;
    int c = i / KPad, kp = i - c * KPad;
    wt[i] = (kp < K) ? f2b(w[kp * NU + c]) : (unsigned short)0;
}

// ---------------- MFMA GEMM: A[Ma][KPAD] x B[Mb][KPAD] -> D[Ma][Mb] ----------------
// MODE 1: A=atoms(gmB), B=units(w1T); out = h1B bf16 [MPAD][512] = swish(D + bias[col])
// MODE 2: A=units(w2T), B=atoms(h1B); out = h2T f32 [512][MPAD] = swish(D + bias[row])
__device__ __forceinline__ void stage8(const unsigned short* gp, unsigned short* lp) {
    __builtin_amdgcn_global_load_lds(
        (const __attribute__((address_space(1))) unsigned int*)gp,
        (__attribute__((address_space(3))) unsigned int*)lp, 16, 0, 0);
}

template<int KPAD, int MODE>
__global__ __launch_bounds__(256) void k_mfma(const unsigned short* __restrict__ A,
                                              const unsigned short* __restrict__ B,
                                              const float* __restrict__ bias,
                                              void* __restrict__ outp) {
    __shared__ __align__(16) unsigned short As[128 * 64];
    __shared__ __align__(16) unsigned short Bs[128 * 64];
    int tid = threadIdx.x;
    int lane = tid & 63, wave = tid >> 6;
    int wm = wave >> 1, wn = wave & 1;
    int quad = lane >> 4, l16 = lane & 15;
    int rowA0 = blockIdx.x * 128, rowB0 = blockIdx.y * 128;

    f32x4 acc[4][4];
    f32x4 zero = {0.f, 0.f, 0.f, 0.f};
#pragma unroll
    for (int i = 0; i < 4; i++)
#pragma unroll
        for (int j = 0; j < 4; j++) acc[i][j] = zero;

    int lrow = lane >> 3;          // 0..7
    int lchk = lane & 7;           // 16B chunk slot

    for (int k0 = 0; k0 < KPAD; k0 += 64) {
        __syncthreads();
        // stage A and B tiles: each wave 32 rows each, 8 rows per instruction,
        // XOR-swizzled chunk placement (chunk c of row r holds global chunk c^(r&7))
#pragma unroll
        for (int i = 0; i < 4; i++) {
            int r = wave * 32 + i * 8 + lrow;
            int gc = lchk ^ (r & 7);
            stage8(A + (size_t)(rowA0 + r) * KPAD + k0 + gc * 8, &As[(wave * 32 + i * 8) * 64]);
        }
#pragma unroll
        for (int i = 0; i < 4; i++) {
            int r = wave * 32 + i * 8 + lrow;
            int gc = lchk ^ (r & 7);
            stage8(B + (size_t)(rowB0 + r) * KPAD + k0 + gc * 8, &Bs[(wave * 32 + i * 8) * 64]);
        }
        __syncthreads();
#pragma unroll
        for (int s = 0; s < 2; s++) {
            bf16x8 af[4], bfr[4];
#pragma unroll
            for (int mt = 0; mt < 4; mt++) {
                int r = wm * 64 + mt * 16 + l16;
                af[mt] = *(const bf16x8*)&As[r * 64 + (((s * 4 + quad) ^ (r & 7)) * 8)];
            }
#pragma unroll
            for (int nt = 0; nt < 4; nt++) {
                int r = wn * 64 + nt * 16 + l16;
                bfr[nt] = *(const bf16x8*)&Bs[r * 64 + (((s * 4 + quad) ^ (r & 7)) * 8)];
            }
#pragma unroll
            for (int mt = 0; mt < 4; mt++)
#pragma unroll
                for (int nt = 0; nt < 4; nt++)
                    acc[mt][nt] = __builtin_amdgcn_mfma_f32_16x16x32_bf16(
                        af[mt], bfr[nt], acc[mt][nt], 0, 0, 0);
        }
    }

    if (MODE == 1) {
        unsigned short* O = (unsigned short*)outp;
#pragma unroll
        for (int nt = 0; nt < 4; nt++) {
            int c = rowB0 + wn * 64 + nt * 16 + l16;
            float b = bias[c];
#pragma unroll
            for (int mt = 0; mt < 4; mt++) {
#pragma unroll
                for (int reg = 0; reg < 4; reg++) {
                    int a = rowA0 + wm * 64 + mt * 16 + quad * 4 + reg;
                    if (a < NA) {
                        float v = acc[mt][nt][reg] + b;
                        O[(size_t)a * NU + c] = f2b(v / (1.f + __expf(-v)));
                    }
                }
            }
        }
    } else {
        float* O = (float*)outp;
#pragma unroll
        for (int mt = 0; mt < 4; mt++) {
#pragma unroll
            for (int reg = 0; reg < 4; reg++) {
                int c = rowA0 + wm * 64 + mt * 16 + quad * 4 + reg;
                float b = bias[c];
#pragma unroll
                for (int nt = 0; nt < 4; nt++) {
                    int a = rowB0 + wn * 64 + nt * 16 + l16;
                    float v = acc[mt][nt][reg] + b;
                    O[(size_t)c * MPAD + a] = v / (1.f + __expf(-v));
                }
            }
        }
    }
}

// ---------------- final layer + per-species scale/shift ----------------
__global__ void k_final(const float* __restrict__ h2T, const float* __restrict__ w3,
                        const float* __restrict__ b3, const int* __restrict__ Z,
                        const float* __restrict__ scale, const float* __restrict__ shift,
                        float* __restrict__ out) {
    int a = blockIdx.x * blockDim.x + threadIdx.x;
    if (a >= NA) return;
    float s = 0.f;
#pragma unroll 8
    for (int c = 0; c < NU; c++) s += w3[c] * h2T[(size_t)c * MPAD + a];
    s += b3[0];
    int z = Z[a];
    out[a] = scale[z] * s + shift[z];
}

extern "C" void kernel_launch(void* const* d_in, const int* in_sizes, int n_in,
                              void* d_out, int out_size, void* d_ws, size_t ws_size,
                              hipStream_t stream) {
    const float* R    = (const float*)d_in[0];
    const int*   Z    = (const int*)  d_in[1];
    const int*   idx  = (const int*)  d_in[2];
    const float* Wr   = (const float*)d_in[3];
    const float* w1   = (const float*)d_in[4];
    const float* b1   = (const float*)d_in[5];
    const float* w2   = (const float*)d_in[6];
    const float* b2   = (const float*)d_in[7];
    const float* w3   = (const float*)d_in[8];
    const float* b3   = (const float*)d_in[9];
    const float* scale= (const float*)d_in[10];
    const float* shift= (const float*)d_in[11];
    float* out = (float*)d_out;
    char* ws = (char*)d_ws;

    // workspace layout (bytes)
    int*            counts = (int*)  (ws + 0);          // 120000
    int*            cursor = (int*)  (ws + 120000);     // 4
    int*            startp = (int*)  (ws + 120064);     // 120000
    int*            wcur   = (int*)  (ws + 240064);     // 120000
    int*            plist  = (int*)  (ws + 360064);     // 4.8 MB -> 5160064
    float*          MT     = (float*)(ws + 5160192);    // 12 MB  -> 17160192
    unsigned short* gmB    = (unsigned short*)(ws + 17160192);  // 30080*384*2 = 23101440 -> 40261632
    unsigned short* w1T    = (unsigned short*)(ws + 40261632);  // 512*384*2 = 393216 -> 40654848
    unsigned short* w2T    = (unsigned short*)(ws + 40654848);  // 512*512*2 = 524288 -> 41179136
    unsigned short* h1B    = (unsigned short*)(ws + 41179136);  // 30080*512*2 = 30801920 -> 71981056
    float*          h2T    = (float*)(ws + 71981056);  // 512*30080*4 = 61603840 -> 133584896

    hipMemsetAsync(counts, 0, 120004, stream);  // counts + cursor

    k_count   <<<(NPAIRS + 255) / 256, 256, 0, stream>>>(idx, counts);
    k_offsets <<<(NA + 255) / 256,     256, 0, stream>>>(counts, startp, wcur, cursor);
    k_fill    <<<(NPAIRS + 255) / 256, 256, 0, stream>>>(idx, Z, wcur, plist);
    k_moments <<<(NA * 4 + 255) / 256, 256, 0, stream>>>(R, Z, Wr, startp, counts, plist, MT);
    k_contract<<<(NA + 127) / 128,     128, 0, stream>>>(MT, gmB);
    k_wt      <<<(NU * KP1 + 255) / 256, 256, 0, stream>>>(w1, w1T, NFEAT, KP1);
    k_wt      <<<(NU * NU  + 255) / 256, 256, 0, stream>>>(w2, w2T, NU, NU);

    k_mfma<KP1, 1><<<dim3(MPAD / 128, NU / 128), 256, 0, stream>>>(gmB, w1T, b1, (void*)h1B);
    k_mfma<NU,  2><<<dim3(NU / 128, MPAD / 128), 256, 0, stream>>>(w2T, h1B, b2, (void*)h2T);

    k_final<<<(NA + 255) / 256, 256, 0, stream>>>(h2T, w3, b3, Z, scale, shift, out);
}

// Round 3
// 385.708 us; speedup vs baseline: 2.0974x; 1.6060x over previous
//
#include <hip/hip_runtime.h>

#define NA      30000
#define MPAD    30080            // 235 * 128
#define NPAIRS  1200000
#define NB      7
#define NK      5
#define NSP     119
#define NFEAT   360
#define KP1     384              // NFEAT padded to 64
#define NU      512
#define WROW    36               // padded W row (35 -> 36 floats, 144B, 16B aligned)

#define BETTA      1.3611111111111112f     // 49/36
#define RADNORM    0.96481348f             // (2*betta/pi)^0.25
#define SHIFT_STEP 0.7857142857142857f     // 5.5/7
#define PI_OVER_R  0.5235987755982988f     // pi/6
#define INV_SQRT7  0.3779644730092272f
#define RMAXV      6.0f

typedef __attribute__((ext_vector_type(8))) short bf16x8;
typedef __attribute__((ext_vector_type(4))) float f32x4;
typedef __attribute__((ext_vector_type(8))) unsigned short u16x8;

__device__ __forceinline__ unsigned short f2b(float x) {
    unsigned u = __float_as_uint(x);
    unsigned r = u + 0x7FFF + ((u >> 16) & 1);   // RNE (inputs are finite)
    return (unsigned short)(r >> 16);
}

// ---------------- CSR build ----------------
__global__ void k_count(const int* __restrict__ idx, int* __restrict__ counts) {
    int p = blockIdx.x * blockDim.x + threadIdx.x;
    if (p < NPAIRS) atomicAdd(&counts[idx[p]], 1);
}

__global__ void k_offsets(const int* __restrict__ counts, int* __restrict__ startp,
                          int* __restrict__ wcur, int* __restrict__ cursor) {
    int a = blockIdx.x * blockDim.x + threadIdx.x;
    if (a < NA) {
        int c = counts[a];
        int s = atomicAdd(cursor, c);
        startp[a] = s;
        wcur[a] = s;
    }
}

__global__ void k_fill(const int* __restrict__ idx, const int* __restrict__ Z,
                       int* __restrict__ wcur, int* __restrict__ plist) {
    int p = blockIdx.x * blockDim.x + threadIdx.x;
    if (p < NPAIRS) {
        int i = idx[p];
        int j = idx[NPAIRS + p];
        int pos = atomicAdd(&wcur[i], 1);
        plist[pos] = j | (Z[j] << 20);
    }
}

// ---------------- prep: pad W rows to 36 floats, R to float4 ----------------
__global__ void k_wpad(const float* __restrict__ W, float* __restrict__ Wp) {
    int i = blockIdx.x * blockDim.x + threadIdx.x;
    if (i >= NSP * NSP * WROW) return;
    int row = i / WROW, e = i - row * WROW;
    Wp[i] = (e < NK * NB) ? W[row * (NK * NB) + e] : 0.f;
}

__global__ void k_rpad(const float* __restrict__ R, float* __restrict__ Rp) {
    int a = blockIdx.x * blockDim.x + threadIdx.x;
    if (a >= NA) return;
    f32x4 v = {R[3*a], R[3*a+1], R[3*a+2], 0.f};
    *(f32x4*)&Rp[4*a] = v;
}

// ---------------- moments: 8 threads per atom, no spills ----------------
// MT layout: [100][NA], u: 0=1, 1..3=n, 4..9=xx,xy,xz,yy,yz,zz, 10..19=3rd order
__global__ __launch_bounds__(256, 2)
void k_moments(const float* __restrict__ Rp, const int* __restrict__ Z,
               const float* __restrict__ Wp,
               const int* __restrict__ startp, const int* __restrict__ counts,
               const int* __restrict__ plist, float* __restrict__ MT) {
    int tid = blockIdx.x * blockDim.x + threadIdx.x;
    int a = tid >> 3, q = tid & 7;
    if (a >= NA) return;
    f32x4 ri = *(const f32x4*)&Rp[4*a];
    int Zi = Z[a];
    float acc[100];
#pragma unroll
    for (int u = 0; u < 100; u++) acc[u] = 0.f;
    int cnt = counts[a], base = startp[a];
    for (int t = q; t < cnt; t += 8) {
        int pk = plist[base + t];
        int j  = pk & 0xFFFFF;
        int Zj = pk >> 20;
        f32x4 rj = *(const f32x4*)&Rp[4*j];
        float dx = rj.x - ri.x, dy = rj.y - ri.y, dz = rj.z - ri.z;
        float d2 = dx*dx + dy*dy + dz*dz + 1e-12f;
        float dr = sqrtf(d2);
        float inv = 1.0f / (dr + 1e-5f);
        float nx = dx*inv, ny = dy*inv, nz = dz*inv;

        // 9 x float4 = padded 36-float W row (16B aligned)
        const f32x4* wrow = (const f32x4*)&Wp[(Zi * NSP + Zj) * WROW];
        f32x4 w4[9];
#pragma unroll
        for (int c = 0; c < 9; c++) w4[c] = wrow[c];
        const float* wf = (const float*)w4;

        float basis[NB];
#pragma unroll
        for (int b = 0; b < NB; b++) {
            float tt = dr - (0.5f + SHIFT_STEP * (float)b);
            basis[b] = RADNORM * __expf(-BETTA * tt * tt);
        }
        float cut = (dr < RMAXV) ? 0.5f * (__cosf(PI_OVER_R * dr) + 1.0f) : 0.0f;
        cut *= INV_SQRT7;
        float rad[NK];
#pragma unroll
        for (int k = 0; k < NK; k++) {
            float s = 0.f;
#pragma unroll
            for (int b = 0; b < NB; b++) s += wf[k*NB + b] * basis[b];
            rad[k] = s * cut;
        }
        float g[20];
        g[0] = 1.f; g[1] = nx; g[2] = ny; g[3] = nz;
        g[4] = nx*nx; g[5] = nx*ny; g[6] = nx*nz; g[7] = ny*ny; g[8] = ny*nz; g[9] = nz*nz;
        g[10] = g[4]*nx; g[11] = g[4]*ny; g[12] = g[4]*nz; g[13] = g[5]*ny; g[14] = g[5]*nz;
        g[15] = g[6]*nz; g[16] = g[7]*ny; g[17] = g[7]*nz; g[18] = g[8]*nz; g[19] = g[9]*nz;
#pragma unroll
        for (int k = 0; k < NK; k++)
#pragma unroll
            for (int u = 0; u < 20; u++)
                acc[k*20 + u] += rad[k] * g[u];
    }
#pragma unroll
    for (int u = 0; u < 100; u++) {
        float v = acc[u];
        v += __shfl_xor(v, 1);
        v += __shfl_xor(v, 2);
        v += __shfl_xor(v, 4);
        acc[u] = v;
    }
    if (q == 0) {
#pragma unroll
        for (int u = 0; u < 100; u++) MT[u * NA + a] = acc[u];
    }
}

// ---------------- contractions -> gmB [MPAD][KP1] bf16 (atom-major, zero-padded) ----
__global__ __launch_bounds__(128, 2)
void k_contract(const float* __restrict__ MT, unsigned short* __restrict__ gmB) {
    int a = blockIdx.x * blockDim.x + threadIdx.x;
    if (a >= NA) return;
    float m0v[5], m1v[5][3], m2s[5][6], m3s[5][10];
#pragma unroll
    for (int k = 0; k < 5; k++) {
        m0v[k] = MT[(k*20 + 0)*NA + a];
#pragma unroll
        for (int i = 0; i < 3; i++)  m1v[k][i] = MT[(k*20 + 1 + i)*NA + a];
#pragma unroll
        for (int u = 0; u < 6; u++)  m2s[k][u] = MT[(k*20 + 4 + u)*NA + a];
#pragma unroll
        for (int u = 0; u < 10; u++) m3s[k][u] = MT[(k*20 + 10 + u)*NA + a];
    }
    const int S2[3][3] = {{0,1,2},{1,3,4},{2,4,5}};
    const int S3[3][3][3] = {
        {{0,1,2},{1,3,4},{2,4,5}},
        {{1,3,4},{3,6,7},{4,7,8}},
        {{2,4,5},{4,7,8},{5,8,9}}
    };
    const float W2U[6]  = {1,2,2,1,2,1};
    const float W3U[10] = {1,3,3,3,6,3,1,3,3,1};
    unsigned short* row = gmB + (size_t)a * KP1;
    u16x8 buf;
    int fcur = 0;
#define EMIT(val) { buf[fcur & 7] = f2b(val); \
                    if ((fcur & 7) == 7) *(u16x8*)&row[fcur - 7] = buf; \
                    fcur++; }
#pragma unroll
    for (int k = 0; k < 5; k++) EMIT(m0v[k]);
#pragma unroll
    for (int r = 0; r < 5; r++)
#pragma unroll
        for (int s = r; s < 5; s++) {
            float v = 0.f;
#pragma unroll
            for (int i = 0; i < 3; i++) v += m1v[r][i] * m1v[s][i];
            EMIT(v);
        }
#pragma unroll
    for (int r = 0; r < 5; r++)
#pragma unroll
        for (int s = r; s < 5; s++) {
            float v = 0.f;
#pragma unroll
            for (int u = 0; u < 6; u++) v += W2U[u] * m2s[r][u] * m2s[s][u];
            EMIT(v);
        }
#pragma unroll
    for (int r = 0; r < 5; r++)
#pragma unroll
        for (int s = r; s < 5; s++) {
            float v = 0.f;
#pragma unroll
            for (int u = 0; u < 10; u++) v += W3U[u] * m3s[r][u] * m3s[s][u];
            EMIT(v);
        }
#pragma unroll
    for (int r = 0; r < 5; r++)
#pragma unroll
        for (int s = r; s < 5; s++)
#pragma unroll
            for (int t = s; t < 5; t++) {
                float v = 0.f;
#pragma unroll
                for (int i = 0; i < 3; i++)
#pragma unroll
                    for (int j = 0; j < 3; j++)
#pragma unroll
                        for (int k = 0; k < 3; k++)
                            v += m2s[r][S2[i][j]] * m2s[s][S2[i][k]] * m2s[t][S2[j][k]];
                EMIT(v);
            }
#pragma unroll
    for (int r = 0; r < 5; r++)
#pragma unroll
        for (int s = r; s < 5; s++)
#pragma unroll
            for (int t = 0; t < 5; t++) {
                float v = 0.f;
#pragma unroll
                for (int i = 0; i < 3; i++)
#pragma unroll
                    for (int j = 0; j < 3; j++)
                        v += m1v[r][i] * m1v[s][j] * m2s[t][S2[i][j]];
                EMIT(v);
            }
#pragma unroll
    for (int r = 0; r < 5; r++)
#pragma unroll
        for (int s = r; s < 5; s++) {
            float T[3][3];
#pragma unroll
            for (int k = 0; k < 3; k++)
#pragma unroll
                for (int l = 0; l < 3; l++) {
                    float v = 0.f;
#pragma unroll
                    for (int i = 0; i < 3; i++)
#pragma unroll
                        for (int j = 0; j < 3; j++)
                            v += m3s[r][S3[i][j][k]] * m3s[s][S3[i][j][l]];
                    T[k][l] = v;
                }
#pragma unroll
            for (int t = 0; t < 5; t++) {
                float v = 0.f;
#pragma unroll
                for (int k = 0; k < 3; k++)
#pragma unroll
                    for (int l = 0; l < 3; l++)
                        v += T[k][l] * m2s[t][S2[k][l]];
                EMIT(v);
            }
        }
#pragma unroll
    for (int r = 0; r < 5; r++)
#pragma unroll
        for (int s = 0; s < 5; s++) {
            float U[3];
#pragma unroll
            for (int k = 0; k < 3; k++) {
                float v = 0.f;
#pragma unroll
                for (int i = 0; i < 3; i++)
#pragma unroll
                    for (int j = 0; j < 3; j++)
                        v += m3s[r][S3[i][j][k]] * m2s[s][S2[i][j]];
                U[k] = v;
            }
#pragma unroll
            for (int t = 0; t < 5; t++)
                EMIT(U[0]*m1v[t][0] + U[1]*m1v[t][1] + U[2]*m1v[t][2]);
        }
    // zero-pad K to 384 (24 more = 3 stores)
#pragma unroll
    for (int z = NFEAT; z < KP1; z++) EMIT(0.f);
#undef EMIT
}

// ---------------- weight transpose+cast: w[K][512] -> wt[512][KPad] bf16, zero-padded
__global__ void k_wt(const float* __restrict__ w, unsigned short* __restrict__ wt,
                     int K, int KPad) {
    int i = blockIdx.x * blockDim.x + threadIdx.x;
    if (i >= NU * KPad) return;
    int c = i / KPad, kp = i - c * KPad;
    wt[i] = (kp < K) ? f2b(w[kp * NU + c]) : (unsigned short)0;
}

// ---------------- MFMA GEMM: A[Ma][KPAD] x B[Mb][KPAD] -> D[Ma][Mb] ----------------
// MODE 1: A=atoms(gmB), B=units(w1T); out = h1B bf16 [MPAD][512] = swish(D + bias[col])
// MODE 2: A=units(w2T), B=atoms(h1B); out = h2T f32 [512][MPAD] = swish(D + bias[row])
__device__ __forceinline__ void stage8(const unsigned short* gp, unsigned short* lp) {
    __builtin_amdgcn_global_load_lds(
        (const __attribute__((address_space(1))) unsigned int*)gp,
        (__attribute__((address_space(3))) unsigned int*)lp, 16, 0, 0);
}

template<int KPAD, int MODE>
__global__ __launch_bounds__(256) void k_mfma(const unsigned short* __restrict__ A,
                                              const unsigned short* __restrict__ B,
                                              const float* __restrict__ bias,
                                              void* __restrict__ outp) {
    __shared__ __align__(16) unsigned short As[128 * 64];
    __shared__ __align__(16) unsigned short Bs[128 * 64];
    int tid = threadIdx.x;
    int lane = tid & 63, wave = tid >> 6;
    int wm = wave >> 1, wn = wave & 1;
    int quad = lane >> 4, l16 = lane & 15;
    int rowA0 = blockIdx.x * 128, rowB0 = blockIdx.y * 128;

    f32x4 acc[4][4];
    f32x4 zero = {0.f, 0.f, 0.f, 0.f};
#pragma unroll
    for (int i = 0; i < 4; i++)
#pragma unroll
        for (int j = 0; j < 4; j++) acc[i][j] = zero;

    int lrow = lane >> 3;          // 0..7
    int lchk = lane & 7;           // 16B chunk slot

    for (int k0 = 0; k0 < KPAD; k0 += 64) {
        __syncthreads();
#pragma unroll
        for (int i = 0; i < 4; i++) {
            int r = wave * 32 + i * 8 + lrow;
            int gc = lchk ^ (r & 7);
            stage8(A + (size_t)(rowA0 + r) * KPAD + k0 + gc * 8, &As[(wave * 32 + i * 8) * 64]);
        }
#pragma unroll
        for (int i = 0; i < 4; i++) {
            int r = wave * 32 + i * 8 + lrow;
            int gc = lchk ^ (r & 7);
            stage8(B + (size_t)(rowB0 + r) * KPAD + k0 + gc * 8, &Bs[(wave * 32 + i * 8) * 64]);
        }
        __syncthreads();
#pragma unroll
        for (int s = 0; s < 2; s++) {
            bf16x8 af[4], bfr[4];
#pragma unroll
            for (int mt = 0; mt < 4; mt++) {
                int r = wm * 64 + mt * 16 + l16;
                af[mt] = *(const bf16x8*)&As[r * 64 + (((s * 4 + quad) ^ (r & 7)) * 8)];
            }
#pragma unroll
            for (int nt = 0; nt < 4; nt++) {
                int r = wn * 64 + nt * 16 + l16;
                bfr[nt] = *(const bf16x8*)&Bs[r * 64 + (((s * 4 + quad) ^ (r & 7)) * 8)];
            }
#pragma unroll
            for (int mt = 0; mt < 4; mt++)
#pragma unroll
                for (int nt = 0; nt < 4; nt++)
                    acc[mt][nt] = __builtin_amdgcn_mfma_f32_16x16x32_bf16(
                        af[mt], bfr[nt], acc[mt][nt], 0, 0, 0);
        }
    }

    if (MODE == 1) {
        unsigned short* O = (unsigned short*)outp;
#pragma unroll
        for (int nt = 0; nt < 4; nt++) {
            int c = rowB0 + wn * 64 + nt * 16 + l16;
            float b = bias[c];
#pragma unroll
            for (int mt = 0; mt < 4; mt++) {
#pragma unroll
                for (int reg = 0; reg < 4; reg++) {
                    int a = rowA0 + wm * 64 + mt * 16 + quad * 4 + reg;
                    if (a < NA) {
                        float v = acc[mt][nt][reg] + b;
                        O[(size_t)a * NU + c] = f2b(v / (1.f + __expf(-v)));
                    }
                }
            }
        }
    } else {
        float* O = (float*)outp;
#pragma unroll
        for (int mt = 0; mt < 4; mt++) {
#pragma unroll
            for (int reg = 0; reg < 4; reg++) {
                int c = rowA0 + wm * 64 + mt * 16 + quad * 4 + reg;
                float b = bias[c];
#pragma unroll
                for (int nt = 0; nt < 4; nt++) {
                    int a = rowB0 + wn * 64 + nt * 16 + l16;
                    float v = acc[mt][nt][reg] + b;
                    O[(size_t)c * MPAD + a] = v / (1.f + __expf(-v));
                }
            }
        }
    }
}

// ---------------- final layer + per-species scale/shift ----------------
__global__ void k_final(const float* __restrict__ h2T, const float* __restrict__ w3,
                        const float* __restrict__ b3, const int* __restrict__ Z,
                        const float* __restrict__ scale, const float* __restrict__ shift,
                        float* __restrict__ out) {
    int a = blockIdx.x * blockDim.x + threadIdx.x;
    if (a >= NA) return;
    float s = 0.f;
#pragma unroll 8
    for (int c = 0; c < NU; c++) s += w3[c] * h2T[(size_t)c * MPAD + a];
    s += b3[0];
    int z = Z[a];
    out[a] = scale[z] * s + shift[z];
}

extern "C" void kernel_launch(void* const* d_in, const int* in_sizes, int n_in,
                              void* d_out, int out_size, void* d_ws, size_t ws_size,
                              hipStream_t stream) {
    const float* R    = (const float*)d_in[0];
    const int*   Z    = (const int*)  d_in[1];
    const int*   idx  = (const int*)  d_in[2];
    const float* Wr   = (const float*)d_in[3];
    const float* w1   = (const float*)d_in[4];
    const float* b1   = (const float*)d_in[5];
    const float* w2   = (const float*)d_in[6];
    const float* b2   = (const float*)d_in[7];
    const float* w3   = (const float*)d_in[8];
    const float* b3   = (const float*)d_in[9];
    const float* scale= (const float*)d_in[10];
    const float* shift= (const float*)d_in[11];
    float* out = (float*)d_out;
    char* ws = (char*)d_ws;

    // workspace layout (bytes)
    int*            counts = (int*)  (ws + 0);          // 120000
    int*            cursor = (int*)  (ws + 120000);     // 4 (pad to 120064)
    int*            startp = (int*)  (ws + 120064);     // 120000
    int*            wcur   = (int*)  (ws + 240064);     // 120000
    int*            plist  = (int*)  (ws + 360064);     // 4.8 MB -> 5160064 (pad 5160192)
    float*          MT     = (float*)(ws + 5160192);    // 12 MB  -> 17160192
    unsigned short* gmB    = (unsigned short*)(ws + 17160192);  // 23101440 -> 40261632
    unsigned short* w1T    = (unsigned short*)(ws + 40261632);  // 393216 -> 40654848
    unsigned short* w2T    = (unsigned short*)(ws + 40654848);  // 524288 -> 41179136
    unsigned short* h1B    = (unsigned short*)(ws + 41179136);  // 30801920 -> 71981056
    float*          h2T    = (float*)(ws + 71981056);  // 61603840 -> 133584896
    // Wpad/Rpad overlay the h2T region (consumed by k_moments, which completes
    // before gemm2 writes h2T on the serial stream)
    float*          Wpad   = (float*)(ws + 71981056);            // 14161*36*4 = 2039184
    float*          Rpad   = (float*)(ws + 71981056 + 2039184);  // 480000

    hipMemsetAsync(counts, 0, 120004, stream);  // counts + cursor

    k_count   <<<(NPAIRS + 255) / 256, 256, 0, stream>>>(idx, counts);
    k_offsets <<<(NA + 255) / 256,     256, 0, stream>>>(counts, startp, wcur, cursor);
    k_fill    <<<(NPAIRS + 255) / 256, 256, 0, stream>>>(idx, Z, wcur, plist);
    k_wpad    <<<(NSP*NSP*WROW + 255) / 256, 256, 0, stream>>>(Wr, Wpad);
    k_rpad    <<<(NA + 255) / 256,     256, 0, stream>>>(R, Rpad);
    k_moments <<<(NA * 8 + 255) / 256, 256, 0, stream>>>(Rpad, Z, Wpad, startp, counts, plist, MT);
    k_contract<<<(NA + 127) / 128,     128, 0, stream>>>(MT, gmB);
    k_wt      <<<(NU * KP1 + 255) / 256, 256, 0, stream>>>(w1, w1T, NFEAT, KP1);
    k_wt      <<<(NU * NU  + 255) / 256, 256, 0, stream>>>(w2, w2T, NU, NU);

    k_mfma<KP1, 1><<<dim3(MPAD / 128, NU / 128), 256, 0, stream>>>(gmB, w1T, b1, (void*)h1B);
    k_mfma<NU,  2><<<dim3(NU / 128, MPAD / 128), 256, 0, stream>>>(w2T, h1B, b2, (void*)h2T);

    k_final<<<(NA + 255) / 256, 256, 0, stream>>>(h2T, w3, b3, Z, scale, shift, out);
}

// Round 4
// 357.135 us; speedup vs baseline: 2.2652x; 1.0800x over previous
//
#include <hip/hip_runtime.h>

#define NA      30000
#define MPAD    30080            // 235 * 128
#define NPAIRS  1200000
#define NB      7
#define NK      5
#define NSP     119
#define NFEAT   360
#define KP1     384              // NFEAT padded to 64
#define NU      512
#define WROW    36               // padded W row (35 -> 36 floats, 144B, 16B aligned)
#define MAXDEG  128              // fixed plist row stride (Poisson(40) tail @128 ~ 0)

#define BETTA      1.3611111111111112f     // 49/36
#define RADNORM    0.96481348f             // (2*betta/pi)^0.25
#define SHIFT_STEP 0.7857142857142857f     // 5.5/7
#define PI_OVER_R  0.5235987755982988f     // pi/6
#define INV_SQRT7  0.3779644730092272f
#define RMAXV      6.0f

typedef __attribute__((ext_vector_type(8))) short bf16x8;
typedef __attribute__((ext_vector_type(4))) float f32x4;

__device__ __forceinline__ unsigned short f2b(float x) {
    unsigned u = __float_as_uint(x);
    unsigned r = u + 0x7FFF + ((u >> 16) & 1);   // RNE (inputs are finite)
    return (unsigned short)(r >> 16);
}

// ---------------- fill: count + scatter in one pass, XCD-binned ----------------
// blockIdx&7 selects an atom octile; assuming blockIdx%8 ~ XCD, each plist row
// is written by one XCD only -> scatter stays in that XCD's L2 (1.9MB window).
__global__ void k_fill2(const int* __restrict__ idx, const int* __restrict__ Z,
                        int* __restrict__ counts, int* __restrict__ plist) {
    int slot = blockIdx.x & 7;
    int blk  = blockIdx.x >> 3;          // 0..63
    int lo = slot * (NA / 8), hi = lo + (NA / 8);
    for (int p = blk * 256 + threadIdx.x; p < NPAIRS; p += 64 * 256) {
        int i = idx[p];
        if (i >= lo && i < hi) {
            int j = idx[NPAIRS + p];
            int r = atomicAdd(&counts[i], 1);
            plist[i * MAXDEG + r] = j | (Z[j] << 20);
        }
    }
}

// ---------------- prep: pad W rows to 36 floats, R to float4 ----------------
__global__ void k_wpad(const float* __restrict__ W, float* __restrict__ Wp) {
    int i = blockIdx.x * blockDim.x + threadIdx.x;
    if (i >= NSP * NSP * WROW) return;
    int row = i / WROW, e = i - row * WROW;
    Wp[i] = (e < NK * NB) ? W[row * (NK * NB) + e] : 0.f;
}

__global__ void k_rpad(const float* __restrict__ R, float* __restrict__ Rp) {
    int a = blockIdx.x * blockDim.x + threadIdx.x;
    if (a >= NA) return;
    f32x4 v = {R[3*a], R[3*a+1], R[3*a+2], 0.f};
    *(f32x4*)&Rp[4*a] = v;
}

// ---------------- moments: 8 threads per atom, no spills ----------------
// MT layout: [100][NA], u: 0=1, 1..3=n, 4..9=xx,xy,xz,yy,yz,zz, 10..19=3rd order
__global__ __launch_bounds__(256, 2)
void k_moments(const float* __restrict__ Rp, const int* __restrict__ Z,
               const float* __restrict__ Wp,
               const int* __restrict__ counts,
               const int* __restrict__ plist, float* __restrict__ MT) {
    int tid = blockIdx.x * blockDim.x + threadIdx.x;
    int a = tid >> 3, q = tid & 7;
    if (a >= NA) return;
    f32x4 ri = *(const f32x4*)&Rp[4*a];
    int Zi = Z[a];
    float acc[100];
#pragma unroll
    for (int u = 0; u < 100; u++) acc[u] = 0.f;
    int cnt = min(counts[a], MAXDEG);
    const int* prow = plist + a * MAXDEG;
    for (int t = q; t < cnt; t += 8) {
        int pk = prow[t];
        int j  = pk & 0xFFFFF;
        int Zj = pk >> 20;
        f32x4 rj = *(const f32x4*)&Rp[4*j];
        float dx = rj.x - ri.x, dy = rj.y - ri.y, dz = rj.z - ri.z;
        float d2 = dx*dx + dy*dy + dz*dz + 1e-12f;
        float dr = sqrtf(d2);
        float inv = 1.0f / (dr + 1e-5f);
        float nx = dx*inv, ny = dy*inv, nz = dz*inv;

        const f32x4* wrow = (const f32x4*)&Wp[(Zi * NSP + Zj) * WROW];
        f32x4 w4[9];
#pragma unroll
        for (int c = 0; c < 9; c++) w4[c] = wrow[c];
        const float* wf = (const float*)w4;

        float basis[NB];
#pragma unroll
        for (int b = 0; b < NB; b++) {
            float tt = dr - (0.5f + SHIFT_STEP * (float)b);
            basis[b] = RADNORM * __expf(-BETTA * tt * tt);
        }
        float cut = (dr < RMAXV) ? 0.5f * (__cosf(PI_OVER_R * dr) + 1.0f) : 0.0f;
        cut *= INV_SQRT7;
        float rad[NK];
#pragma unroll
        for (int k = 0; k < NK; k++) {
            float s = 0.f;
#pragma unroll
            for (int b = 0; b < NB; b++) s += wf[k*NB + b] * basis[b];
            rad[k] = s * cut;
        }
        float g[20];
        g[0] = 1.f; g[1] = nx; g[2] = ny; g[3] = nz;
        g[4] = nx*nx; g[5] = nx*ny; g[6] = nx*nz; g[7] = ny*ny; g[8] = ny*nz; g[9] = nz*nz;
        g[10] = g[4]*nx; g[11] = g[4]*ny; g[12] = g[4]*nz; g[13] = g[5]*ny; g[14] = g[5]*nz;
        g[15] = g[6]*nz; g[16] = g[7]*ny; g[17] = g[7]*nz; g[18] = g[8]*nz; g[19] = g[9]*nz;
#pragma unroll
        for (int k = 0; k < NK; k++)
#pragma unroll
            for (int u = 0; u < 20; u++)
                acc[k*20 + u] += rad[k] * g[u];
    }
#pragma unroll
    for (int u = 0; u < 100; u++) {
        float v = acc[u];
        v += __shfl_xor(v, 1);
        v += __shfl_xor(v, 2);
        v += __shfl_xor(v, 4);
        acc[u] = v;
    }
    if (q == 0) {
#pragma unroll
        for (int u = 0; u < 100; u++) MT[u * NA + a] = acc[u];
    }
}

// ---------------- contractions: block = 64 atoms in LDS, 4 waves split features ----
// lane = atom (LDS stride-1 across lanes, 2-way aliasing = free)
__global__ __launch_bounds__(256)
void k_contract(const float* __restrict__ MT, unsigned short* __restrict__ gmB) {
    __shared__ float M[100 * 64];
    int tid = threadIdx.x;
    int lane = tid & 63;
    int wave = tid >> 6;
    int a0 = blockIdx.x * 64;
    int a = a0 + lane;

    for (int e = tid; e < 6400; e += 256) {
        int u = e >> 6, l = e & 63;
        int aa = a0 + l;
        M[e] = (aa < NA) ? MT[u * NA + aa] : 0.f;
    }
    __syncthreads();

    const int S2[3][3] = {{0,1,2},{1,3,4},{2,4,5}};
    const int S3[3][3][3] = {
        {{0,1,2},{1,3,4},{2,4,5}},
        {{1,3,4},{3,6,7},{4,7,8}},
        {{2,4,5},{4,7,8},{5,8,9}}
    };
    bool ok = (a < NA);
    unsigned short* row = gmB + (size_t)a * KP1;
#define LD(comp) M[(comp) * 64 + lane]

    if (wave == 0) {
        // m0: f 0..4
        if (ok) {
            for (int k = 0; k < 5; k++) row[k] = f2b(LD(k * 20));
        }
        int f = 5;
        // c1: f 5..19
        for (int r = 0; r < 5; r++)
            for (int s = r; s < 5; s++) {
                float v = 0.f;
#pragma unroll
                for (int i = 0; i < 3; i++) v += LD(r*20+1+i) * LD(s*20+1+i);
                if (ok) row[f] = f2b(v);
                f++;
            }
        // c2: f 20..34
        const float W2U[6] = {1,2,2,1,2,1};
        for (int r = 0; r < 5; r++)
            for (int s = r; s < 5; s++) {
                float v = 0.f;
#pragma unroll
                for (int u = 0; u < 6; u++) v += W2U[u] * LD(r*20+4+u) * LD(s*20+4+u);
                if (ok) row[f] = f2b(v);
                f++;
            }
        // c3: f 35..49
        const float W3U[10] = {1,3,3,3,6,3,1,3,3,1};
        for (int r = 0; r < 5; r++)
            for (int s = r; s < 5; s++) {
                float v = 0.f;
#pragma unroll
                for (int u = 0; u < 10; u++) v += W3U[u] * LD(r*20+10+u) * LD(s*20+10+u);
                if (ok) row[f] = f2b(v);
                f++;
            }
        // c4: f 50..84 (tri3)
        for (int r = 0; r < 5; r++) {
            float m2r[6];
#pragma unroll
            for (int u = 0; u < 6; u++) m2r[u] = LD(r*20+4+u);
            for (int s = r; s < 5; s++) {
                float m2q[6];
#pragma unroll
                for (int u = 0; u < 6; u++) m2q[u] = LD(s*20+4+u);
                for (int t = s; t < 5; t++) {
                    float m2t[6];
#pragma unroll
                    for (int u = 0; u < 6; u++) m2t[u] = LD(t*20+4+u);
                    float v = 0.f;
#pragma unroll
                    for (int i = 0; i < 3; i++)
#pragma unroll
                        for (int j = 0; j < 3; j++)
#pragma unroll
                            for (int k = 0; k < 3; k++)
                                v += m2r[S2[i][j]] * m2q[S2[i][k]] * m2t[S2[j][k]];
                    if (ok) row[f] = f2b(v);
                    f++;
                }
            }
        }
    } else if (wave == 1) {
        // c5: f 85..159  (pair-major, t fastest)
        int f = 85;
        for (int r = 0; r < 5; r++) {
            float m1r[3];
#pragma unroll
            for (int i = 0; i < 3; i++) m1r[i] = LD(r*20+1+i);
            for (int s = r; s < 5; s++) {
                float m1q[3];
#pragma unroll
                for (int i = 0; i < 3; i++) m1q[i] = LD(s*20+1+i);
                for (int t = 0; t < 5; t++) {
                    float m2t[6];
#pragma unroll
                    for (int u = 0; u < 6; u++) m2t[u] = LD(t*20+4+u);
                    float v = 0.f;
#pragma unroll
                    for (int i = 0; i < 3; i++)
#pragma unroll
                        for (int j = 0; j < 3; j++)
                            v += m1r[i] * m1q[j] * m2t[S2[i][j]];
                    if (ok) row[f] = f2b(v);
                    f++;
                }
            }
        }
        // c7: f 235..359  (full r,s; t fastest)
        f = 235;
        for (int r = 0; r < 5; r++) {
            float m3r[10];
#pragma unroll
            for (int u = 0; u < 10; u++) m3r[u] = LD(r*20+10+u);
            for (int s = 0; s < 5; s++) {
                float m2q[6];
#pragma unroll
                for (int u = 0; u < 6; u++) m2q[u] = LD(s*20+4+u);
                float U0 = 0.f, U1 = 0.f, U2 = 0.f;
#pragma unroll
                for (int i = 0; i < 3; i++)
#pragma unroll
                    for (int j = 0; j < 3; j++) {
                        float w = m2q[S2[i][j]];
                        U0 += m3r[S3[i][j][0]] * w;
                        U1 += m3r[S3[i][j][1]] * w;
                        U2 += m3r[S3[i][j][2]] * w;
                    }
                for (int t = 0; t < 5; t++) {
                    float v = U0 * LD(t*20+1) + U1 * LD(t*20+2) + U2 * LD(t*20+3);
                    if (ok) row[f] = f2b(v);
                    f++;
                }
            }
        }
    } else {
        // c6: f 160..234, 15 rs-pairs split: wave2 -> pairs 0..6, wave3 -> 7..14
        int pbeg = (wave == 2) ? 0 : 7;
        int pend = (wave == 2) ? 7 : 15;
        int p = 0;
        for (int r = 0; r < 5; r++)
            for (int s = r; s < 5; s++) {
                if (p >= pbeg && p < pend) {
                    float m3r[10], m3q[10];
#pragma unroll
                    for (int u = 0; u < 10; u++) m3r[u] = LD(r*20+10+u);
#pragma unroll
                    for (int u = 0; u < 10; u++) m3q[u] = LD(s*20+10+u);
                    float T[3][3];
#pragma unroll
                    for (int k = 0; k < 3; k++)
#pragma unroll
                        for (int l = 0; l < 3; l++) {
                            float v = 0.f;
#pragma unroll
                            for (int i = 0; i < 3; i++)
#pragma unroll
                                for (int j = 0; j < 3; j++)
                                    v += m3r[S3[i][j][k]] * m3q[S3[i][j][l]];
                            T[k][l] = v;
                        }
                    int f = 160 + p * 5;
                    for (int t = 0; t < 5; t++) {
                        float m2t[6];
#pragma unroll
                        for (int u = 0; u < 6; u++) m2t[u] = LD(t*20+4+u);
                        float v = 0.f;
#pragma unroll
                        for (int k = 0; k < 3; k++)
#pragma unroll
                            for (int l = 0; l < 3; l++)
                                v += T[k][l] * m2t[S2[k][l]];
                        if (ok) row[f + t] = f2b(v);
                    }
                }
                p++;
            }
        // zero-pad K 360..383 (wave 3)
        if (wave == 3 && ok) {
            for (int z = NFEAT; z < KP1; z++) row[z] = 0;
        }
    }
#undef LD
}

// ---------------- weight transpose+cast: w[K][512] -> wt[512][KPad] bf16, zero-padded
__global__ void k_wt(const float* __restrict__ w, unsigned short* __restrict__ wt,
                     int K, int KPad) {
    int i = blockIdx.x * blockDim.x + threadIdx.x;
    if (i >= NU * KPad) return;
    int c = i / KPad, kp = i - c * KPad;
    wt[i] = (kp < K) ? f2b(w[kp * NU + c]) : (unsigned short)0;
}

// ---------------- MFMA GEMM: A[Ma][KPAD] x B[Mb][KPAD] -> D[Ma][Mb] ----------------
// MODE 1: A=atoms(gmB), B=units(w1T); out = h1B bf16 [MPAD][512] = swish(D + bias[col])
// MODE 2: A=units(w2T), B=atoms(h1B); out = h2T f32 [512][MPAD] = swish(D + bias[row])
__device__ __forceinline__ void stage8(const unsigned short* gp, unsigned short* lp) {
    __builtin_amdgcn_global_load_lds(
        (const __attribute__((address_space(1))) unsigned int*)gp,
        (__attribute__((address_space(3))) unsigned int*)lp, 16, 0, 0);
}

template<int KPAD, int MODE>
__global__ __launch_bounds__(256) void k_mfma(const unsigned short* __restrict__ A,
                                              const unsigned short* __restrict__ B,
                                              const float* __restrict__ bias,
                                              void* __restrict__ outp) {
    __shared__ __align__(16) unsigned short As[128 * 64];
    __shared__ __align__(16) unsigned short Bs[128 * 64];
    int tid = threadIdx.x;
    int lane = tid & 63, wave = tid >> 6;
    int wm = wave >> 1, wn = wave & 1;
    int quad = lane >> 4, l16 = lane & 15;
    int rowA0 = blockIdx.x * 128, rowB0 = blockIdx.y * 128;

    f32x4 acc[4][4];
    f32x4 zero = {0.f, 0.f, 0.f, 0.f};
#pragma unroll
    for (int i = 0; i < 4; i++)
#pragma unroll
        for (int j = 0; j < 4; j++) acc[i][j] = zero;

    int lrow = lane >> 3;          // 0..7
    int lchk = lane & 7;           // 16B chunk slot

    for (int k0 = 0; k0 < KPAD; k0 += 64) {
        __syncthreads();
#pragma unroll
        for (int i = 0; i < 4; i++) {
            int r = wave * 32 + i * 8 + lrow;
            int gc = lchk ^ (r & 7);
            stage8(A + (size_t)(rowA0 + r) * KPAD + k0 + gc * 8, &As[(wave * 32 + i * 8) * 64]);
        }
#pragma unroll
        for (int i = 0; i < 4; i++) {
            int r = wave * 32 + i * 8 + lrow;
            int gc = lchk ^ (r & 7);
            stage8(B + (size_t)(rowB0 + r) * KPAD + k0 + gc * 8, &Bs[(wave * 32 + i * 8) * 64]);
        }
        __syncthreads();
#pragma unroll
        for (int s = 0; s < 2; s++) {
            bf16x8 af[4], bfr[4];
#pragma unroll
            for (int mt = 0; mt < 4; mt++) {
                int r = wm * 64 + mt * 16 + l16;
                af[mt] = *(const bf16x8*)&As[r * 64 + (((s * 4 + quad) ^ (r & 7)) * 8)];
            }
#pragma unroll
            for (int nt = 0; nt < 4; nt++) {
                int r = wn * 64 + nt * 16 + l16;
                bfr[nt] = *(const bf16x8*)&Bs[r * 64 + (((s * 4 + quad) ^ (r & 7)) * 8)];
            }
#pragma unroll
            for (int mt = 0; mt < 4; mt++)
#pragma unroll
                for (int nt = 0; nt < 4; nt++)
                    acc[mt][nt] = __builtin_amdgcn_mfma_f32_16x16x32_bf16(
                        af[mt], bfr[nt], acc[mt][nt], 0, 0, 0);
        }
    }

    if (MODE == 1) {
        unsigned short* O = (unsigned short*)outp;
#pragma unroll
        for (int nt = 0; nt < 4; nt++) {
            int c = rowB0 + wn * 64 + nt * 16 + l16;
            float b = bias[c];
#pragma unroll
            for (int mt = 0; mt < 4; mt++) {
#pragma unroll
                for (int reg = 0; reg < 4; reg++) {
                    int a = rowA0 + wm * 64 + mt * 16 + quad * 4 + reg;
                    if (a < NA) {
                        float v = acc[mt][nt][reg] + b;
                        O[(size_t)a * NU + c] = f2b(v / (1.f + __expf(-v)));
                    }
                }
            }
        }
    } else {
        float* O = (float*)outp;
#pragma unroll
        for (int mt = 0; mt < 4; mt++) {
#pragma unroll
            for (int reg = 0; reg < 4; reg++) {
                int c = rowA0 + wm * 64 + mt * 16 + quad * 4 + reg;
                float b = bias[c];
#pragma unroll
                for (int nt = 0; nt < 4; nt++) {
                    int a = rowB0 + wn * 64 + nt * 16 + l16;
                    float v = acc[mt][nt][reg] + b;
                    O[(size_t)c * MPAD + a] = v / (1.f + __expf(-v));
                }
            }
        }
    }
}

// ---------------- final layer + per-species scale/shift ----------------
__global__ void k_final(const float* __restrict__ h2T, const float* __restrict__ w3,
                        const float* __restrict__ b3, const int* __restrict__ Z,
                        const float* __restrict__ scale, const float* __restrict__ shift,
                        float* __restrict__ out) {
    int a = blockIdx.x * blockDim.x + threadIdx.x;
    if (a >= NA) return;
    float s = 0.f;
#pragma unroll 8
    for (int c = 0; c < NU; c++) s += w3[c] * h2T[(size_t)c * MPAD + a];
    s += b3[0];
    int z = Z[a];
    out[a] = scale[z] * s + shift[z];
}

extern "C" void kernel_launch(void* const* d_in, const int* in_sizes, int n_in,
                              void* d_out, int out_size, void* d_ws, size_t ws_size,
                              hipStream_t stream) {
    const float* R    = (const float*)d_in[0];
    const int*   Z    = (const int*)  d_in[1];
    const int*   idx  = (const int*)  d_in[2];
    const float* Wr   = (const float*)d_in[3];
    const float* w1   = (const float*)d_in[4];
    const float* b1   = (const float*)d_in[5];
    const float* w2   = (const float*)d_in[6];
    const float* b2   = (const float*)d_in[7];
    const float* w3   = (const float*)d_in[8];
    const float* b3   = (const float*)d_in[9];
    const float* scale= (const float*)d_in[10];
    const float* shift= (const float*)d_in[11];
    float* out = (float*)d_out;
    char* ws = (char*)d_ws;

    // workspace layout (bytes)
    int*            counts = (int*)  (ws + 0);          // 120000 (pad 120064)
    int*            plist  = (int*)  (ws + 120064);     // 30000*128*4 = 15360000 -> 15480064
    float*          MT     = (float*)(ws + 15480064);   // 12000000 -> 27480064
    unsigned short* gmB    = (unsigned short*)(ws + 27480064);  // 23101440 -> 50581504
    unsigned short* w1T    = (unsigned short*)(ws + 50581504);  // 393216 -> 50974720
    unsigned short* w2T    = (unsigned short*)(ws + 50974720);  // 524288 -> 51499008
    unsigned short* h1B    = (unsigned short*)(ws + 51499008);  // 30801920 -> 82300928
    float*          h2T    = (float*)(ws + 82300928);   // 61603840 -> 143904768
    // Wpad/Rpad overlay the h2T region (consumed by k_moments, which completes
    // before gemm2 writes h2T on the serial stream)
    float*          Wpad   = (float*)(ws + 82300928);            // 14161*36*4 = 2039184
    float*          Rpad   = (float*)(ws + 82300928 + 2039184);  // 480000

    hipMemsetAsync(counts, 0, 120000, stream);

    k_fill2   <<<512, 256, 0, stream>>>(idx, Z, counts, plist);
    k_wpad    <<<(NSP*NSP*WROW + 255) / 256, 256, 0, stream>>>(Wr, Wpad);
    k_rpad    <<<(NA + 255) / 256,     256, 0, stream>>>(R, Rpad);
    k_moments <<<(NA * 8 + 255) / 256, 256, 0, stream>>>(Rpad, Z, Wpad, counts, plist, MT);
    k_contract<<<(NA + 63) / 64,       256, 0, stream>>>(MT, gmB);
    k_wt      <<<(NU * KP1 + 255) / 256, 256, 0, stream>>>(w1, w1T, NFEAT, KP1);
    k_wt      <<<(NU * NU  + 255) / 256, 256, 0, stream>>>(w2, w2T, NU, NU);

    k_mfma<KP1, 1><<<dim3(MPAD / 128, NU / 128), 256, 0, stream>>>(gmB, w1T, b1, (void*)h1B);
    k_mfma<NU,  2><<<dim3(NU / 128, MPAD / 128), 256, 0, stream>>>(w2T, h1B, b2, (void*)h2T);

    k_final<<<(NA + 255) / 256, 256, 0, stream>>>(h2T, w3, b3, Z, scale, shift, out);
}

// Round 6
// 289.435 us; speedup vs baseline: 2.7950x; 1.2339x over previous
//
#include <hip/hip_runtime.h>

#define NA      30000
#define MPAD    30080            // 235 * 128
#define NPAIRS  1200000
#define NB      7
#define NK      5
#define NSP     119
#define NFEAT   360
#define KP1     384              // NFEAT padded to 64
#define NU      512
#define WROW    36               // padded W row (35 -> 36 floats, 144B, 16B aligned)
#define MAXSLOT 120              // plist slots per atom (Poisson(40): P(deg>120) ~ 0)
#define PSTRIDE 128              // plist row stride in ints (alignment)
#define NBK     118              // coarse buckets of 256 atoms (ceil(30000/256))
#define BCAP    11520            // entries per coarse bucket (mean 10240, sd ~101)
#define PPB     4688             // pairs per partition block (256 blocks)

#define BETTA      1.3611111111111112f     // 49/36
#define RADNORM    0.96481348f             // (2*betta/pi)^0.25
#define SHIFT_STEP 0.7857142857142857f     // 5.5/7
#define PI_OVER_R  0.5235987755982988f     // pi/6
#define INV_SQRT7  0.3779644730092272f
#define RMAXV      6.0f

typedef __attribute__((ext_vector_type(8))) short bf16x8;
typedef __attribute__((ext_vector_type(4))) float f32x4;

__device__ __forceinline__ unsigned short f2b(float x) {
    unsigned u = __float_as_uint(x);
    unsigned r = u + 0x7FFF + ((u >> 16) & 1);   // RNE (inputs are finite)
    return (unsigned short)(r >> 16);
}

// ---------------- phase 1: partition pairs into 118 coarse buckets ----------------
// entry pack: (i&255)<<22 | Zj<<15 | j   (iloc 8b, Zj 7b, j 15b)
__global__ __launch_bounds__(256)
void k_part(const int* __restrict__ idx, const int* __restrict__ Z,
            int* __restrict__ gcur, int* __restrict__ part) {
    __shared__ int hist[NBK];
    __shared__ int base[NBK];
    int tid = threadIdx.x;
    for (int b = tid; b < NBK; b += 256) hist[b] = 0;
    __syncthreads();
    int p0 = blockIdx.x * PPB;
    int p1 = min(p0 + PPB, NPAIRS);
    for (int p = p0 + tid; p < p1; p += 256)
        atomicAdd(&hist[idx[p] >> 8], 1);
    __syncthreads();
    for (int b = tid; b < NBK; b += 256) {
        base[b] = atomicAdd(&gcur[b], hist[b]);
        hist[b] = 0;
    }
    __syncthreads();
    for (int p = p0 + tid; p < p1; p += 256) {
        int i = idx[p];
        int b = i >> 8;
        int j = idx[NPAIRS + p];
        int zj = Z[j];
        int off = base[b] + atomicAdd(&hist[b], 1);
        if (off < BCAP)
            part[b * BCAP + off] = ((i & 255) << 22) | (zj << 15) | j;
    }
}

// ---------------- phase 2: coarse buckets -> dense CSR rows (coalesced writes) ----
__global__ __launch_bounds__(256)
void k_csr(const int* __restrict__ part, const int* __restrict__ gcnt,
           int* __restrict__ counts, int* __restrict__ plist) {
    __shared__ int lp[128 * MAXSLOT];   // 61440 B
    __shared__ int lc[128];
    int tid = threadIdx.x;
    int lane = tid & 63, wave = tid >> 6;
    int w = blockIdx.x;                 // 128-atom window, 0..234
    int cb = w >> 1;                    // coarse bucket
    int par = w & 1;                    // which 128-half of the 256-atom bucket
    for (int t = tid; t < 128; t += 256) lc[t] = 0;
    __syncthreads();
    int n = min(gcnt[cb], BCAP);
    for (int e = tid; e < n; e += 256) {
        int v = part[cb * BCAP + e];
        int iloc = v >> 22;             // 0..255
        if ((iloc >> 7) == par) {
            int i7 = iloc & 127;
            int r = atomicAdd(&lc[i7], 1);
            if (r < MAXSLOT) lp[i7 * MAXSLOT + r] = v & 0x3FFFFF;  // Zj<<15 | j
        }
    }
    __syncthreads();
    for (int t = tid; t < 128; t += 256) {
        int a = w * 128 + t;
        if (a < NA) counts[a] = min(lc[t], MAXSLOT);
    }
    // coalesced row writes: each wave 32 rows (4 waves x 32 = 128 rows)
    for (int rr = 0; rr < 32; rr++) {
        int row = wave * 32 + rr;
        int a = w * 128 + row;
        if (a < NA) {
            for (int c = lane; c < MAXSLOT; c += 64)
                plist[(size_t)a * PSTRIDE + c] = lp[row * MAXSLOT + c];
        }
    }
}

// ---------------- prep: pad W rows to 36 floats, R to float4 ----------------
__global__ void k_wpad(const float* __restrict__ W, float* __restrict__ Wp) {
    int i = blockIdx.x * blockDim.x + threadIdx.x;
    if (i >= NSP * NSP * WROW) return;
    int row = i / WROW, e = i - row * WROW;
    Wp[i] = (e < NK * NB) ? W[row * (NK * NB) + e] : 0.f;
}

__global__ void k_rpad(const float* __restrict__ R, float* __restrict__ Rp) {
    int a = blockIdx.x * blockDim.x + threadIdx.x;
    if (a >= NA) return;
    f32x4 v = {R[3*a], R[3*a+1], R[3*a+2], 0.f};
    *(f32x4*)&Rp[4*a] = v;
}

// ---------------- moments: 8 threads per atom, no spills ----------------
// MT layout: [100][NA], u: 0=1, 1..3=n, 4..9=xx,xy,xz,yy,yz,zz, 10..19=3rd order
__global__ __launch_bounds__(256, 2)
void k_moments(const float* __restrict__ Rp, const int* __restrict__ Z,
               const float* __restrict__ Wp,
               const int* __restrict__ counts,
               const int* __restrict__ plist, float* __restrict__ MT) {
    int tid = blockIdx.x * blockDim.x + threadIdx.x;
    int a = tid >> 3, q = tid & 7;
    if (a >= NA) return;
    f32x4 ri = *(const f32x4*)&Rp[4*a];
    int Zi = Z[a];
    float acc[100];
#pragma unroll
    for (int u = 0; u < 100; u++) acc[u] = 0.f;
    int cnt = min(counts[a], MAXSLOT);
    const int* prow = plist + (size_t)a * PSTRIDE;
    for (int t = q; t < cnt; t += 8) {
        int pk = prow[t];
        int j  = pk & 0x7FFF;
        int Zj = (pk >> 15) & 0x7F;
        f32x4 rj = *(const f32x4*)&Rp[4*j];
        float dx = rj.x - ri.x, dy = rj.y - ri.y, dz = rj.z - ri.z;
        float d2 = dx*dx + dy*dy + dz*dz + 1e-12f;
        float dr = sqrtf(d2);
        float inv = 1.0f / (dr + 1e-5f);
        float nx = dx*inv, ny = dy*inv, nz = dz*inv;

        const f32x4* wrow = (const f32x4*)&Wp[(Zi * NSP + Zj) * WROW];
        f32x4 w4[9];
#pragma unroll
        for (int c = 0; c < 9; c++) w4[c] = wrow[c];
        const float* wf = (const float*)w4;

        float basis[NB];
#pragma unroll
        for (int b = 0; b < NB; b++) {
            float tt = dr - (0.5f + SHIFT_STEP * (float)b);
            basis[b] = RADNORM * __expf(-BETTA * tt * tt);
        }
        float cut = (dr < RMAXV) ? 0.5f * (__cosf(PI_OVER_R * dr) + 1.0f) : 0.0f;
        cut *= INV_SQRT7;
        float rad[NK];
#pragma unroll
        for (int k = 0; k < NK; k++) {
            float s = 0.f;
#pragma unroll
            for (int b = 0; b < NB; b++) s += wf[k*NB + b] * basis[b];
            rad[k] = s * cut;
        }
        float g[20];
        g[0] = 1.f; g[1] = nx; g[2] = ny; g[3] = nz;
        g[4] = nx*nx; g[5] = nx*ny; g[6] = nx*nz; g[7] = ny*ny; g[8] = ny*nz; g[9] = nz*nz;
        g[10] = g[4]*nx; g[11] = g[4]*ny; g[12] = g[4]*nz; g[13] = g[5]*ny; g[14] = g[5]*nz;
        g[15] = g[6]*nz; g[16] = g[7]*ny; g[17] = g[7]*nz; g[18] = g[8]*nz; g[19] = g[9]*nz;
#pragma unroll
        for (int k = 0; k < NK; k++)
#pragma unroll
            for (int u = 0; u < 20; u++)
                acc[k*20 + u] += rad[k] * g[u];
    }
#pragma unroll
    for (int u = 0; u < 100; u++) {
        float v = acc[u];
        v += __shfl_xor(v, 1);
        v += __shfl_xor(v, 2);
        v += __shfl_xor(v, 4);
        acc[u] = v;
    }
    if (q == 0) {
#pragma unroll
        for (int u = 0; u < 100; u++) MT[u * NA + a] = acc[u];
    }
}

// ---------------- contractions: block = 64 atoms in LDS, 4 waves split features ----
__global__ __launch_bounds__(256)
void k_contract(const float* __restrict__ MT, unsigned short* __restrict__ gmB) {
    __shared__ float M[100 * 64];
    int tid = threadIdx.x;
    int lane = tid & 63;
    int wave = tid >> 6;
    int a0 = blockIdx.x * 64;
    int a = a0 + lane;

    for (int e = tid; e < 6400; e += 256) {
        int u = e >> 6, l = e & 63;
        int aa = a0 + l;
        M[e] = (aa < NA) ? MT[u * NA + aa] : 0.f;
    }
    __syncthreads();

    const int S2[3][3] = {{0,1,2},{1,3,4},{2,4,5}};
    const int S3[3][3][3] = {
        {{0,1,2},{1,3,4},{2,4,5}},
        {{1,3,4},{3,6,7},{4,7,8}},
        {{2,4,5},{4,7,8},{5,8,9}}
    };
    bool ok = (a < NA);
    unsigned short* row = gmB + (size_t)a * KP1;
#define LD(comp) M[(comp) * 64 + lane]

    if (wave == 0) {
        if (ok) {
            for (int k = 0; k < 5; k++) row[k] = f2b(LD(k * 20));
        }
        int f = 5;
        for (int r = 0; r < 5; r++)
            for (int s = r; s < 5; s++) {
                float v = 0.f;
#pragma unroll
                for (int i = 0; i < 3; i++) v += LD(r*20+1+i) * LD(s*20+1+i);
                if (ok) row[f] = f2b(v);
                f++;
            }
        const float W2U[6] = {1,2,2,1,2,1};
        for (int r = 0; r < 5; r++)
            for (int s = r; s < 5; s++) {
                float v = 0.f;
#pragma unroll
                for (int u = 0; u < 6; u++) v += W2U[u] * LD(r*20+4+u) * LD(s*20+4+u);
                if (ok) row[f] = f2b(v);
                f++;
            }
        const float W3U[10] = {1,3,3,3,6,3,1,3,3,1};
        for (int r = 0; r < 5; r++)
            for (int s = r; s < 5; s++) {
                float v = 0.f;
#pragma unroll
                for (int u = 0; u < 10; u++) v += W3U[u] * LD(r*20+10+u) * LD(s*20+10+u);
                if (ok) row[f] = f2b(v);
                f++;
            }
        for (int r = 0; r < 5; r++) {
            float m2r[6];
#pragma unroll
            for (int u = 0; u < 6; u++) m2r[u] = LD(r*20+4+u);
            for (int s = r; s < 5; s++) {
                float m2q[6];
#pragma unroll
                for (int u = 0; u < 6; u++) m2q[u] = LD(s*20+4+u);
                for (int t = s; t < 5; t++) {
                    float m2t[6];
#pragma unroll
                    for (int u = 0; u < 6; u++) m2t[u] = LD(t*20+4+u);
                    float v = 0.f;
#pragma unroll
                    for (int i = 0; i < 3; i++)
#pragma unroll
                        for (int j = 0; j < 3; j++)
#pragma unroll
                            for (int k = 0; k < 3; k++)
                                v += m2r[S2[i][j]] * m2q[S2[i][k]] * m2t[S2[j][k]];
                    if (ok) row[f] = f2b(v);
                    f++;
                }
            }
        }
    } else if (wave == 1) {
        int f = 85;
        for (int r = 0; r < 5; r++) {
            float m1r[3];
#pragma unroll
            for (int i = 0; i < 3; i++) m1r[i] = LD(r*20+1+i);
            for (int s = r; s < 5; s++) {
                float m1q[3];
#pragma unroll
                for (int i = 0; i < 3; i++) m1q[i] = LD(s*20+1+i);
                for (int t = 0; t < 5; t++) {
                    float m2t[6];
#pragma unroll
                    for (int u = 0; u < 6; u++) m2t[u] = LD(t*20+4+u);
                    float v = 0.f;
#pragma unroll
                    for (int i = 0; i < 3; i++)
#pragma unroll
                        for (int j = 0; j < 3; j++)
                            v += m1r[i] * m1q[j] * m2t[S2[i][j]];
                    if (ok) row[f] = f2b(v);
                    f++;
                }
            }
        }
        f = 235;
        for (int r = 0; r < 5; r++) {
            float m3r[10];
#pragma unroll
            for (int u = 0; u < 10; u++) m3r[u] = LD(r*20+10+u);
            for (int s = 0; s < 5; s++) {
                float m2q[6];
#pragma unroll
                for (int u = 0; u < 6; u++) m2q[u] = LD(s*20+4+u);
                float U0 = 0.f, U1 = 0.f, U2 = 0.f;
#pragma unroll
                for (int i = 0; i < 3; i++)
#pragma unroll
                    for (int j = 0; j < 3; j++) {
                        float ww = m2q[S2[i][j]];
                        U0 += m3r[S3[i][j][0]] * ww;
                        U1 += m3r[S3[i][j][1]] * ww;
                        U2 += m3r[S3[i][j][2]] * ww;
                    }
                for (int t = 0; t < 5; t++) {
                    float v = U0 * LD(t*20+1) + U1 * LD(t*20+2) + U2 * LD(t*20+3);
                    if (ok) row[f] = f2b(v);
                    f++;
                }
            }
        }
    } else {
        int pbeg = (wave == 2) ? 0 : 7;
        int pend = (wave == 2) ? 7 : 15;
        int p = 0;
        for (int r = 0; r < 5; r++)
            for (int s = r; s < 5; s++) {
                if (p >= pbeg && p < pend) {
                    float m3r[10], m3q[10];
#pragma unroll
                    for (int u = 0; u < 10; u++) m3r[u] = LD(r*20+10+u);
#pragma unroll
                    for (int u = 0; u < 10; u++) m3q[u] = LD(s*20+10+u);
                    float T[3][3];
#pragma unroll
                    for (int k = 0; k < 3; k++)
#pragma unroll
                        for (int l = 0; l < 3; l++) {
                            float v = 0.f;
#pragma unroll
                            for (int i = 0; i < 3; i++)
#pragma unroll
                                for (int j = 0; j < 3; j++)
                                    v += m3r[S3[i][j][k]] * m3q[S3[i][j][l]];
                            T[k][l] = v;
                        }
                    int f = 160 + p * 5;
                    for (int t = 0; t < 5; t++) {
                        float m2t[6];
#pragma unroll
                        for (int u = 0; u < 6; u++) m2t[u] = LD(t*20+4+u);
                        float v = 0.f;
#pragma unroll
                        for (int k = 0; k < 3; k++)
#pragma unroll
                            for (int l = 0; l < 3; l++)
                                v += T[k][l] * m2t[S2[k][l]];
                        if (ok) row[f + t] = f2b(v);
                    }
                }
                p++;
            }
        if (wave == 3 && ok) {
            for (int z = NFEAT; z < KP1; z++) row[z] = 0;
        }
    }
#undef LD
}

// ---------------- weight transpose+cast: w[K][512] -> wt[512][KPad] bf16 ----------
__global__ void k_wt(const float* __restrict__ w, unsigned short* __restrict__ wt,
                     int K, int KPad) {
    int i = blockIdx.x * blockDim.x + threadIdx.x;
    if (i >= NU * KPad) return;
    int c = i / KPad, kp = i - c * KPad;
    wt[i] = (kp < K) ? f2b(w[kp * NU + c]) : (unsigned short)0;
}

// ---------------- MFMA GEMM: A[Ma][KPAD] x B[Mb][KPAD] -> D[Ma][Mb] ----------------
// MODE 1: A=atoms(gmB), B=units(w1T); out h1B bf16 [MPAD][512] = swish(D + bias[col])
// MODE 2: A=units(w2T), B=atoms(h1B); fused layer-3: atomicAdd w3[c]*swish(D+bias[c])
__device__ __forceinline__ void stage8(const unsigned short* gp, unsigned short* lp) {
    __builtin_amdgcn_global_load_lds(
        (const __attribute__((address_space(1))) unsigned int*)gp,
        (__attribute__((address_space(3))) unsigned int*)lp, 16, 0, 0);
}

template<int KPAD, int MODE>
__global__ __launch_bounds__(256) void k_mfma(const unsigned short* __restrict__ A,
                                              const unsigned short* __restrict__ B,
                                              const float* __restrict__ bias,
                                              const float* __restrict__ w3,
                                              void* __restrict__ outp) {
    __shared__ __align__(16) unsigned short As[128 * 64];
    __shared__ __align__(16) unsigned short Bs[128 * 64];
    __shared__ float red[2][2][4][16];
    int tid = threadIdx.x;
    int lane = tid & 63, wave = tid >> 6;
    int wm = wave >> 1, wn = wave & 1;
    int quad = lane >> 4, l16 = lane & 15;
    int rowA0 = blockIdx.x * 128, rowB0 = blockIdx.y * 128;

    f32x4 acc[4][4];
    f32x4 zero = {0.f, 0.f, 0.f, 0.f};
#pragma unroll
    for (int i = 0; i < 4; i++)
#pragma unroll
        for (int j = 0; j < 4; j++) acc[i][j] = zero;

    int lrow = lane >> 3;          // 0..7
    int lchk = lane & 7;           // 16B chunk slot

    for (int k0 = 0; k0 < KPAD; k0 += 64) {
        __syncthreads();
#pragma unroll
        for (int i = 0; i < 4; i++) {
            int r = wave * 32 + i * 8 + lrow;
            int gc = lchk ^ (r & 7);
            stage8(A + (size_t)(rowA0 + r) * KPAD + k0 + gc * 8, &As[(wave * 32 + i * 8) * 64]);
        }
#pragma unroll
        for (int i = 0; i < 4; i++) {
            int r = wave * 32 + i * 8 + lrow;
            int gc = lchk ^ (r & 7);
            stage8(B + (size_t)(rowB0 + r) * KPAD + k0 + gc * 8, &Bs[(wave * 32 + i * 8) * 64]);
        }
        __syncthreads();
#pragma unroll
        for (int s = 0; s < 2; s++) {
            bf16x8 af[4], bfr[4];
#pragma unroll
            for (int mt = 0; mt < 4; mt++) {
                int r = wm * 64 + mt * 16 + l16;
                af[mt] = *(const bf16x8*)&As[r * 64 + (((s * 4 + quad) ^ (r & 7)) * 8)];
            }
#pragma unroll
            for (int nt = 0; nt < 4; nt++) {
                int r = wn * 64 + nt * 16 + l16;
                bfr[nt] = *(const bf16x8*)&Bs[r * 64 + (((s * 4 + quad) ^ (r & 7)) * 8)];
            }
#pragma unroll
            for (int mt = 0; mt < 4; mt++)
#pragma unroll
                for (int nt = 0; nt < 4; nt++)
                    acc[mt][nt] = __builtin_amdgcn_mfma_f32_16x16x32_bf16(
                        af[mt], bfr[nt], acc[mt][nt], 0, 0, 0);
        }
    }

    if (MODE == 1) {
        unsigned short* O = (unsigned short*)outp;
#pragma unroll
        for (int nt = 0; nt < 4; nt++) {
            int c = rowB0 + wn * 64 + nt * 16 + l16;
            float b = bias[c];
#pragma unroll
            for (int mt = 0; mt < 4; mt++) {
#pragma unroll
                for (int reg = 0; reg < 4; reg++) {
                    int a = rowA0 + wm * 64 + mt * 16 + quad * 4 + reg;
                    if (a < NA) {
                        float v = acc[mt][nt][reg] + b;
                        O[(size_t)a * NU + c] = f2b(v / (1.f + __expf(-v)));
                    }
                }
            }
        }
    } else {
        // fused layer-3 partial dot: per-lane over its 16 c's, then quad + wm reduce
        float pn[4] = {0.f, 0.f, 0.f, 0.f};
#pragma unroll
        for (int mt = 0; mt < 4; mt++) {
#pragma unroll
            for (int reg = 0; reg < 4; reg++) {
                int c = rowA0 + wm * 64 + mt * 16 + quad * 4 + reg;
                float b = bias[c];
                float w3c = w3[c];
#pragma unroll
                for (int nt = 0; nt < 4; nt++) {
                    float v = acc[mt][nt][reg] + b;
                    pn[nt] += w3c * (v / (1.f + __expf(-v)));
                }
            }
        }
#pragma unroll
        for (int nt = 0; nt < 4; nt++) {
            pn[nt] += __shfl_xor(pn[nt], 16);
            pn[nt] += __shfl_xor(pn[nt], 32);
        }
        if (quad == 0) {
#pragma unroll
            for (int nt = 0; nt < 4; nt++) red[wm][wn][nt][l16] = pn[nt];
        }
        __syncthreads();
        if (tid < 128) {
            int wn2 = tid >> 6, nt2 = (tid >> 4) & 3, lb = tid & 15;
            float s = red[0][wn2][nt2][lb] + red[1][wn2][nt2][lb];
            int a = rowB0 + wn2 * 64 + nt2 * 16 + lb;
            if (a < NA) atomicAdd((float*)outp + a, s);
        }
    }
}

// ---------------- finish: out = scale[Z]*(out + b3) + shift[Z] ----------------
__global__ void k_finish(float* __restrict__ out, const float* __restrict__ b3,
                         const int* __restrict__ Z, const float* __restrict__ scale,
                         const float* __restrict__ shift) {
    int a = blockIdx.x * blockDim.x + threadIdx.x;
    if (a >= NA) return;
    int z = Z[a];
    out[a] = scale[z] * (out[a] + b3[0]) + shift[z];
}

extern "C" void kernel_launch(void* const* d_in, const int* in_sizes, int n_in,
                              void* d_out, int out_size, void* d_ws, size_t ws_size,
                              hipStream_t stream) {
    const float* R    = (const float*)d_in[0];
    const int*   Z    = (const int*)  d_in[1];
    const int*   idx  = (const int*)  d_in[2];
    const float* Wr   = (const float*)d_in[3];
    const float* w1   = (const float*)d_in[4];
    const float* b1   = (const float*)d_in[5];
    const float* w2   = (const float*)d_in[6];
    const float* b2   = (const float*)d_in[7];
    const float* w3   = (const float*)d_in[8];
    const float* b3   = (const float*)d_in[9];
    const float* scale= (const float*)d_in[10];
    const float* shift= (const float*)d_in[11];
    float* out = (float*)d_out;
    char* ws = (char*)d_ws;

    // workspace layout (bytes)
    int*            gcur   = (int*)  (ws + 0);           // 512
    int*            counts = (int*)  (ws + 512);         // 120000 -> 120576 (padded)
    int*            part   = (int*)  (ws + 120576);      // 118*11520*4 = 5437440 -> 5558016
    int*            plist  = (int*)  (ws + 5558016);     // 30000*128*4 = 15360000 -> 20918016
    float*          MT     = (float*)(ws + 20918016);    // 12000000 -> 32918016
    unsigned short* gmB    = (unsigned short*)(ws + 32918016);  // 23101440 -> 56019456
    unsigned short* w1T    = (unsigned short*)(ws + 56019456);  // 393216 -> 56412672
    unsigned short* w2T    = (unsigned short*)(ws + 56412672);  // 524288 -> 56936960
    unsigned short* h1B    = (unsigned short*)(ws + 56936960);  // 30801920 -> 87738880
    float*          Wpad   = (float*)(ws + 87738880);    // 14161*36*4 = 2039184 -> 89778064
    float*          Rpad   = (float*)(ws + 89778064);    // 480000 -> 90258064

    hipMemsetAsync(gcur, 0, 512, stream);
    hipMemsetAsync(d_out, 0, NA * sizeof(float), stream);   // layer-3 accumulator

    k_part    <<<256, 256, 0, stream>>>(idx, Z, gcur, part);
    k_csr     <<<235, 256, 0, stream>>>(part, gcur, counts, plist);
    k_wpad    <<<(NSP*NSP*WROW + 255) / 256, 256, 0, stream>>>(Wr, Wpad);
    k_rpad    <<<(NA + 255) / 256,     256, 0, stream>>>(R, Rpad);
    k_moments <<<(NA * 8 + 255) / 256, 256, 0, stream>>>(Rpad, Z, Wpad, counts, plist, MT);
    k_contract<<<(NA + 63) / 64,       256, 0, stream>>>(MT, gmB);
    k_wt      <<<(NU * KP1 + 255) / 256, 256, 0, stream>>>(w1, w1T, NFEAT, KP1);
    k_wt      <<<(NU * NU  + 255) / 256, 256, 0, stream>>>(w2, w2T, NU, NU);

    k_mfma<KP1, 1><<<dim3(MPAD / 128, NU / 128), 256, 0, stream>>>(gmB, w1T, b1, nullptr, (void*)h1B);
    k_mfma<NU,  2><<<dim3(NU / 128, MPAD / 128), 256, 0, stream>>>(w2T, h1B, b2, w3, (void*)out);

    k_finish<<<(NA + 255) / 256, 256, 0, stream>>>(out, b3, Z, scale, shift);
}

// Round 7
// 270.992 us; speedup vs baseline: 2.9853x; 1.0681x over previous
//
#include <hip/hip_runtime.h>

#define NA      30000
#define MPAD    30080            // 235 * 128
#define NPAIRS  1200000
#define NB      7
#define NK      5
#define NSP     119
#define NFEAT   360
#define KP1     384              // NFEAT padded to 64
#define NU      512
#define WROW    36               // padded W row (35 -> 36 floats, 144B, 16B aligned)
#define MAXSLOT 120              // plist slots per atom (Poisson(40): P(deg>120) ~ 0)
#define PSTRIDE 128              // plist row stride in ints (alignment)
#define NBK     118              // coarse buckets of 256 atoms (ceil(30000/256))
#define BCAP    11520            // entries per coarse bucket (mean 10240, sd ~101)
#define PPB     4688             // pairs per partition block (256 blocks)
#define NTILE   235              // 128-atom tiles

#define BETTA      1.3611111111111112f     // 49/36
#define RADNORM    0.96481348f             // (2*betta/pi)^0.25
#define SHIFT_STEP 0.7857142857142857f     // 5.5/7
#define PI_OVER_R  0.5235987755982988f     // pi/6
#define INV_SQRT7  0.3779644730092272f
#define RMAXV      6.0f

typedef __attribute__((ext_vector_type(8))) short bf16x8;
typedef __attribute__((ext_vector_type(4))) float f32x4;

__device__ __forceinline__ unsigned short f2b(float x) {
    unsigned u = __float_as_uint(x);
    unsigned r = u + 0x7FFF + ((u >> 16) & 1);   // RNE (inputs are finite)
    return (unsigned short)(r >> 16);
}

// ---------------- phase 1: partition pairs into 118 coarse buckets ----------------
// entry pack: (i&255)<<22 | Zj<<15 | j   (iloc 8b, Zj 7b, j 15b)
__global__ __launch_bounds__(256)
void k_part(const int* __restrict__ idx, const int* __restrict__ Z,
            int* __restrict__ gcur, int* __restrict__ part) {
    __shared__ int hist[NBK];
    __shared__ int base[NBK];
    int tid = threadIdx.x;
    for (int b = tid; b < NBK; b += 256) hist[b] = 0;
    __syncthreads();
    int p0 = blockIdx.x * PPB;
    int p1 = min(p0 + PPB, NPAIRS);
    for (int p = p0 + tid; p < p1; p += 256)
        atomicAdd(&hist[idx[p] >> 8], 1);
    __syncthreads();
    for (int b = tid; b < NBK; b += 256) {
        base[b] = atomicAdd(&gcur[b], hist[b]);
        hist[b] = 0;
    }
    __syncthreads();
    for (int p = p0 + tid; p < p1; p += 256) {
        int i = idx[p];
        int b = i >> 8;
        int j = idx[NPAIRS + p];
        int zj = Z[j];
        int off = base[b] + atomicAdd(&hist[b], 1);
        if (off < BCAP)
            part[b * BCAP + off] = ((i & 255) << 22) | (zj << 15) | j;
    }
}

// ---------------- phase 2: coarse buckets -> dense CSR rows (coalesced writes) ----
__global__ __launch_bounds__(256)
void k_csr(const int* __restrict__ part, const int* __restrict__ gcnt,
           int* __restrict__ counts, int* __restrict__ plist) {
    __shared__ int lp[128 * MAXSLOT];   // 61440 B
    __shared__ int lc[128];
    int tid = threadIdx.x;
    int lane = tid & 63, wave = tid >> 6;
    int w = blockIdx.x;                 // 128-atom window, 0..234
    int cb = w >> 1;                    // coarse bucket
    int par = w & 1;                    // which 128-half of the 256-atom bucket
    for (int t = tid; t < 128; t += 256) lc[t] = 0;
    __syncthreads();
    int n = min(gcnt[cb], BCAP);
    for (int e = tid; e < n; e += 256) {
        int v = part[cb * BCAP + e];
        int iloc = v >> 22;             // 0..255
        if ((iloc >> 7) == par) {
            int i7 = iloc & 127;
            int r = atomicAdd(&lc[i7], 1);
            if (r < MAXSLOT) lp[i7 * MAXSLOT + r] = v & 0x3FFFFF;  // Zj<<15 | j
        }
    }
    __syncthreads();
    for (int t = tid; t < 128; t += 256) {
        int a = w * 128 + t;
        if (a < NA) counts[a] = min(lc[t], MAXSLOT);
    }
    // coalesced row writes: each wave 32 rows (4 waves x 32 = 128 rows)
    for (int rr = 0; rr < 32; rr++) {
        int row = wave * 32 + rr;
        int a = w * 128 + row;
        if (a < NA) {
            for (int c = lane; c < MAXSLOT; c += 64)
                plist[(size_t)a * PSTRIDE + c] = lp[row * MAXSLOT + c];
        }
    }
}

// ---------------- merged prep: Wpad, Rpad, w1T, w2T in one launch ----------------
#define PREP_W   (NSP*NSP*WROW)          // 509796
#define PREP_R   NA                      // 30000
#define PREP_W1  (NU*KP1)                // 196608
#define PREP_W2  (NU*NU)                 // 262144
#define PREP_TOT (PREP_W + PREP_R + PREP_W1 + PREP_W2)
__global__ void k_prep(const float* __restrict__ W, const float* __restrict__ R,
                       const float* __restrict__ w1, const float* __restrict__ w2,
                       float* __restrict__ Wp, float* __restrict__ Rp,
                       unsigned short* __restrict__ w1T, unsigned short* __restrict__ w2T) {
    int i = blockIdx.x * blockDim.x + threadIdx.x;
    if (i < PREP_W) {
        int row = i / WROW, e = i - row * WROW;
        Wp[i] = (e < NK * NB) ? W[row * (NK * NB) + e] : 0.f;
        return;
    }
    i -= PREP_W;
    if (i < PREP_R) {
        f32x4 v = {R[3*i], R[3*i+1], R[3*i+2], 0.f};
        *(f32x4*)&Rp[4*i] = v;
        return;
    }
    i -= PREP_R;
    if (i < PREP_W1) {
        int c = i / KP1, kp = i - c * KP1;
        w1T[i] = (kp < NFEAT) ? f2b(w1[kp * NU + c]) : (unsigned short)0;
        return;
    }
    i -= PREP_W1;
    if (i < PREP_W2) {
        int c = i >> 9, kp = i & 511;
        w2T[i] = f2b(w2[kp * NU + c]);
    }
}

// ---------------- moments: 8 threads per atom, no spills ----------------
// MT layout: [100][NA], u: 0=1, 1..3=n, 4..9=xx,xy,xz,yy,yz,zz, 10..19=3rd order
__global__ __launch_bounds__(256, 2)
void k_moments(const float* __restrict__ Rp, const int* __restrict__ Z,
               const float* __restrict__ Wp,
               const int* __restrict__ counts,
               const int* __restrict__ plist, float* __restrict__ MT) {
    int tid = blockIdx.x * blockDim.x + threadIdx.x;
    int a = tid >> 3, q = tid & 7;
    if (a >= NA) return;
    f32x4 ri = *(const f32x4*)&Rp[4*a];
    int Zi = Z[a];
    float acc[100];
#pragma unroll
    for (int u = 0; u < 100; u++) acc[u] = 0.f;
    int cnt = min(counts[a], MAXSLOT);
    const int* prow = plist + (size_t)a * PSTRIDE;
    for (int t = q; t < cnt; t += 8) {
        int pk = prow[t];
        int j  = pk & 0x7FFF;
        int Zj = (pk >> 15) & 0x7F;
        f32x4 rj = *(const f32x4*)&Rp[4*j];
        float dx = rj.x - ri.x, dy = rj.y - ri.y, dz = rj.z - ri.z;
        float d2 = dx*dx + dy*dy + dz*dz + 1e-12f;
        float dr = sqrtf(d2);
        float inv = 1.0f / (dr + 1e-5f);
        float nx = dx*inv, ny = dy*inv, nz = dz*inv;

        const f32x4* wrow = (const f32x4*)&Wp[(Zi * NSP + Zj) * WROW];
        f32x4 w4[9];
#pragma unroll
        for (int c = 0; c < 9; c++) w4[c] = wrow[c];
        const float* wf = (const float*)w4;

        float basis[NB];
#pragma unroll
        for (int b = 0; b < NB; b++) {
            float tt = dr - (0.5f + SHIFT_STEP * (float)b);
            basis[b] = RADNORM * __expf(-BETTA * tt * tt);
        }
        float cut = (dr < RMAXV) ? 0.5f * (__cosf(PI_OVER_R * dr) + 1.0f) : 0.0f;
        cut *= INV_SQRT7;
        float rad[NK];
#pragma unroll
        for (int k = 0; k < NK; k++) {
            float s = 0.f;
#pragma unroll
            for (int b = 0; b < NB; b++) s += wf[k*NB + b] * basis[b];
            rad[k] = s * cut;
        }
        float g[20];
        g[0] = 1.f; g[1] = nx; g[2] = ny; g[3] = nz;
        g[4] = nx*nx; g[5] = nx*ny; g[6] = nx*nz; g[7] = ny*ny; g[8] = ny*nz; g[9] = nz*nz;
        g[10] = g[4]*nx; g[11] = g[4]*ny; g[12] = g[4]*nz; g[13] = g[5]*ny; g[14] = g[5]*nz;
        g[15] = g[6]*nz; g[16] = g[7]*ny; g[17] = g[7]*nz; g[18] = g[8]*nz; g[19] = g[9]*nz;
#pragma unroll
        for (int k = 0; k < NK; k++)
#pragma unroll
            for (int u = 0; u < 20; u++)
                acc[k*20 + u] += rad[k] * g[u];
    }
#pragma unroll
    for (int u = 0; u < 100; u++) {
        float v = acc[u];
        v += __shfl_xor(v, 1);
        v += __shfl_xor(v, 2);
        v += __shfl_xor(v, 4);
        acc[u] = v;
    }
    if (q == 0) {
#pragma unroll
        for (int u = 0; u < 100; u++) MT[u * NA + a] = acc[u];
    }
}

// ---------------- contractions: block = 64 atoms in LDS, 4 waves split features ----
__global__ __launch_bounds__(256)
void k_contract(const float* __restrict__ MT, unsigned short* __restrict__ gmB) {
    __shared__ float M[100 * 64];
    int tid = threadIdx.x;
    int lane = tid & 63;
    int wave = tid >> 6;
    int a0 = blockIdx.x * 64;
    int a = a0 + lane;

    for (int e = tid; e < 6400; e += 256) {
        int u = e >> 6, l = e & 63;
        int aa = a0 + l;
        M[e] = (aa < NA) ? MT[u * NA + aa] : 0.f;
    }
    __syncthreads();

    const int S2[3][3] = {{0,1,2},{1,3,4},{2,4,5}};
    const int S3[3][3][3] = {
        {{0,1,2},{1,3,4},{2,4,5}},
        {{1,3,4},{3,6,7},{4,7,8}},
        {{2,4,5},{4,7,8},{5,8,9}}
    };
    bool ok = (a < NA);
    unsigned short* row = gmB + (size_t)a * KP1;
#define LD(comp) M[(comp) * 64 + lane]

    if (wave == 0) {
        if (ok) {
            for (int k = 0; k < 5; k++) row[k] = f2b(LD(k * 20));
        }
        int f = 5;
        for (int r = 0; r < 5; r++)
            for (int s = r; s < 5; s++) {
                float v = 0.f;
#pragma unroll
                for (int i = 0; i < 3; i++) v += LD(r*20+1+i) * LD(s*20+1+i);
                if (ok) row[f] = f2b(v);
                f++;
            }
        const float W2U[6] = {1,2,2,1,2,1};
        for (int r = 0; r < 5; r++)
            for (int s = r; s < 5; s++) {
                float v = 0.f;
#pragma unroll
                for (int u = 0; u < 6; u++) v += W2U[u] * LD(r*20+4+u) * LD(s*20+4+u);
                if (ok) row[f] = f2b(v);
                f++;
            }
        const float W3U[10] = {1,3,3,3,6,3,1,3,3,1};
        for (int r = 0; r < 5; r++)
            for (int s = r; s < 5; s++) {
                float v = 0.f;
#pragma unroll
                for (int u = 0; u < 10; u++) v += W3U[u] * LD(r*20+10+u) * LD(s*20+10+u);
                if (ok) row[f] = f2b(v);
                f++;
            }
        for (int r = 0; r < 5; r++) {
            float m2r[6];
#pragma unroll
            for (int u = 0; u < 6; u++) m2r[u] = LD(r*20+4+u);
            for (int s = r; s < 5; s++) {
                float m2q[6];
#pragma unroll
                for (int u = 0; u < 6; u++) m2q[u] = LD(s*20+4+u);
                for (int t = s; t < 5; t++) {
                    float m2t[6];
#pragma unroll
                    for (int u = 0; u < 6; u++) m2t[u] = LD(t*20+4+u);
                    float v = 0.f;
#pragma unroll
                    for (int i = 0; i < 3; i++)
#pragma unroll
                        for (int j = 0; j < 3; j++)
#pragma unroll
                            for (int k = 0; k < 3; k++)
                                v += m2r[S2[i][j]] * m2q[S2[i][k]] * m2t[S2[j][k]];
                    if (ok) row[f] = f2b(v);
                    f++;
                }
            }
        }
    } else if (wave == 1) {
        int f = 85;
        for (int r = 0; r < 5; r++) {
            float m1r[3];
#pragma unroll
            for (int i = 0; i < 3; i++) m1r[i] = LD(r*20+1+i);
            for (int s = r; s < 5; s++) {
                float m1q[3];
#pragma unroll
                for (int i = 0; i < 3; i++) m1q[i] = LD(s*20+1+i);
                for (int t = 0; t < 5; t++) {
                    float m2t[6];
#pragma unroll
                    for (int u = 0; u < 6; u++) m2t[u] = LD(t*20+4+u);
                    float v = 0.f;
#pragma unroll
                    for (int i = 0; i < 3; i++)
#pragma unroll
                        for (int j = 0; j < 3; j++)
                            v += m1r[i] * m1q[j] * m2t[S2[i][j]];
                    if (ok) row[f] = f2b(v);
                    f++;
                }
            }
        }
        f = 235;
        for (int r = 0; r < 5; r++) {
            float m3r[10];
#pragma unroll
            for (int u = 0; u < 10; u++) m3r[u] = LD(r*20+10+u);
            for (int s = 0; s < 5; s++) {
                float m2q[6];
#pragma unroll
                for (int u = 0; u < 6; u++) m2q[u] = LD(s*20+4+u);
                float U0 = 0.f, U1 = 0.f, U2 = 0.f;
#pragma unroll
                for (int i = 0; i < 3; i++)
#pragma unroll
                    for (int j = 0; j < 3; j++) {
                        float ww = m2q[S2[i][j]];
                        U0 += m3r[S3[i][j][0]] * ww;
                        U1 += m3r[S3[i][j][1]] * ww;
                        U2 += m3r[S3[i][j][2]] * ww;
                    }
                for (int t = 0; t < 5; t++) {
                    float v = U0 * LD(t*20+1) + U1 * LD(t*20+2) + U2 * LD(t*20+3);
                    if (ok) row[f] = f2b(v);
                    f++;
                }
            }
        }
    } else {
        int pbeg = (wave == 2) ? 0 : 7;
        int pend = (wave == 2) ? 7 : 15;
        int p = 0;
        for (int r = 0; r < 5; r++)
            for (int s = r; s < 5; s++) {
                if (p >= pbeg && p < pend) {
                    float m3r[10], m3q[10];
#pragma unroll
                    for (int u = 0; u < 10; u++) m3r[u] = LD(r*20+10+u);
#pragma unroll
                    for (int u = 0; u < 10; u++) m3q[u] = LD(s*20+10+u);
                    float T[3][3];
#pragma unroll
                    for (int k = 0; k < 3; k++)
#pragma unroll
                        for (int l = 0; l < 3; l++) {
                            float v = 0.f;
#pragma unroll
                            for (int i = 0; i < 3; i++)
#pragma unroll
                                for (int j = 0; j < 3; j++)
                                    v += m3r[S3[i][j][k]] * m3q[S3[i][j][l]];
                            T[k][l] = v;
                        }
                    int f = 160 + p * 5;
                    for (int t = 0; t < 5; t++) {
                        float m2t[6];
#pragma unroll
                        for (int u = 0; u < 6; u++) m2t[u] = LD(t*20+4+u);
                        float v = 0.f;
#pragma unroll
                        for (int k = 0; k < 3; k++)
#pragma unroll
                            for (int l = 0; l < 3; l++)
                                v += T[k][l] * m2t[S2[k][l]];
                        if (ok) row[f + t] = f2b(v);
                    }
                }
                p++;
            }
        if (wave == 3 && ok) {
            for (int z = NFEAT; z < KP1; z++) row[z] = 0;
        }
    }
#undef LD
}

// ---------------- MFMA GEMM, persistent 2 atom-tiles per block -------------------
// MODE 1: A=atoms(gmB), B=units(w1T); h1B bf16 [MPAD][512] = swish(D + bias[col]),
//         written via LDS-staged coalesced stores.
// MODE 2: A=units(w2T), B=atoms(h1B); fused layer-3: atomicAdd w3[c]*swish(D+bias[c])
__device__ __forceinline__ void stage8(const unsigned short* gp, unsigned short* lp) {
    __builtin_amdgcn_global_load_lds(
        (const __attribute__((address_space(1))) unsigned int*)gp,
        (__attribute__((address_space(3))) unsigned int*)lp, 16, 0, 0);
}

template<int KPAD, int MODE>
__global__ __launch_bounds__(256) void k_mfma(const unsigned short* __restrict__ A,
                                              const unsigned short* __restrict__ B,
                                              const float* __restrict__ bias,
                                              const float* __restrict__ w3,
                                              void* __restrict__ outp) {
    // SMEM union: [As 16KB | Bs 16KB | red 1KB]  or  [Ot 128x136 shorts = 34816B]
    __shared__ __align__(16) unsigned char SMEM[35072];
    unsigned short* As = (unsigned short*)SMEM;
    unsigned short* Bs = (unsigned short*)(SMEM + 16384);
    float* red = (float*)(SMEM + 32768);       // [2][2][4][16]
    int tid = threadIdx.x;
    int lane = tid & 63, wave = tid >> 6;
    int wm = wave >> 1, wn = wave & 1;
    int quad = lane >> 4, l16 = lane & 15;
    int lrow = lane >> 3;          // 0..7
    int lchk = lane & 7;           // 16B chunk slot

    for (int t = 0; t < 2; t++) {
        int atile = blockIdx.y * 2 + t;
        if (atile >= NTILE) break;
        int rowA0, rowB0;
        if (MODE == 1) { rowA0 = atile * 128;      rowB0 = blockIdx.x * 128; }
        else           { rowA0 = blockIdx.x * 128; rowB0 = atile * 128; }

        f32x4 acc[4][4];
        f32x4 zero = {0.f, 0.f, 0.f, 0.f};
#pragma unroll
        for (int i = 0; i < 4; i++)
#pragma unroll
            for (int j = 0; j < 4; j++) acc[i][j] = zero;

        for (int k0 = 0; k0 < KPAD; k0 += 64) {
            __syncthreads();
#pragma unroll
            for (int i = 0; i < 4; i++) {
                int r = wave * 32 + i * 8 + lrow;
                int gc = lchk ^ (r & 7);
                stage8(A + (size_t)(rowA0 + r) * KPAD + k0 + gc * 8, &As[(wave * 32 + i * 8) * 64]);
            }
#pragma unroll
            for (int i = 0; i < 4; i++) {
                int r = wave * 32 + i * 8 + lrow;
                int gc = lchk ^ (r & 7);
                stage8(B + (size_t)(rowB0 + r) * KPAD + k0 + gc * 8, &Bs[(wave * 32 + i * 8) * 64]);
            }
            __syncthreads();
#pragma unroll
            for (int s = 0; s < 2; s++) {
                bf16x8 af[4], bfr[4];
#pragma unroll
                for (int mt = 0; mt < 4; mt++) {
                    int r = wm * 64 + mt * 16 + l16;
                    af[mt] = *(const bf16x8*)&As[r * 64 + (((s * 4 + quad) ^ (r & 7)) * 8)];
                }
#pragma unroll
                for (int nt = 0; nt < 4; nt++) {
                    int r = wn * 64 + nt * 16 + l16;
                    bfr[nt] = *(const bf16x8*)&Bs[r * 64 + (((s * 4 + quad) ^ (r & 7)) * 8)];
                }
#pragma unroll
                for (int mt = 0; mt < 4; mt++)
#pragma unroll
                    for (int nt = 0; nt < 4; nt++)
                        acc[mt][nt] = __builtin_amdgcn_mfma_f32_16x16x32_bf16(
                            af[mt], bfr[nt], acc[mt][nt], 0, 0, 0);
            }
        }

        if (MODE == 1) {
            // stage swish output tile in LDS (stride 136 shorts), then coalesced store
            __syncthreads();   // all waves done reading As/Bs
            unsigned short* Ot = (unsigned short*)SMEM;
#pragma unroll
            for (int nt = 0; nt < 4; nt++) {
                int c_loc = wn * 64 + nt * 16 + l16;
                float b = bias[rowB0 + c_loc];
#pragma unroll
                for (int mt = 0; mt < 4; mt++) {
#pragma unroll
                    for (int reg = 0; reg < 4; reg++) {
                        int a_loc = wm * 64 + mt * 16 + quad * 4 + reg;
                        float v = acc[mt][nt][reg] + b;
                        Ot[a_loc * 136 + c_loc] = f2b(v / (1.f + __expf(-v)));
                    }
                }
            }
            __syncthreads();
            unsigned short* O = (unsigned short*)outp;
            int half = lane >> 5, l32 = lane & 31;
#pragma unroll
            for (int it = 0; it < 16; it++) {
                int rloc = wave * 32 + it * 2 + half;
                int a = rowA0 + rloc;
                unsigned long long d = *(const unsigned long long*)&Ot[rloc * 136 + l32 * 4];
                if (a < NA)
                    *(unsigned long long*)&O[(size_t)a * NU + rowB0 + l32 * 4] = d;
            }
        } else {
            // fused layer-3 partial dot: per-lane over its 16 c's, quad + wm reduce
            float pn[4] = {0.f, 0.f, 0.f, 0.f};
#pragma unroll
            for (int mt = 0; mt < 4; mt++) {
#pragma unroll
                for (int reg = 0; reg < 4; reg++) {
                    int c = rowA0 + wm * 64 + mt * 16 + quad * 4 + reg;
                    float b = bias[c];
                    float w3c = w3[c];
#pragma unroll
                    for (int nt = 0; nt < 4; nt++) {
                        float v = acc[mt][nt][reg] + b;
                        pn[nt] += w3c * (v / (1.f + __expf(-v)));
                    }
                }
            }
#pragma unroll
            for (int nt = 0; nt < 4; nt++) {
                pn[nt] += __shfl_xor(pn[nt], 16);
                pn[nt] += __shfl_xor(pn[nt], 32);
            }
            __syncthreads();   // As/Bs done; red region safe vs previous tile
            if (quad == 0) {
#pragma unroll
                for (int nt = 0; nt < 4; nt++)
                    red[((wm * 2 + wn) * 4 + nt) * 16 + l16] = pn[nt];
            }
            __syncthreads();
            if (tid < 128) {
                int wn2 = tid >> 6, nt2 = (tid >> 4) & 3, lb = tid & 15;
                float s = red[((0 * 2 + wn2) * 4 + nt2) * 16 + lb]
                        + red[((1 * 2 + wn2) * 4 + nt2) * 16 + lb];
                int a = rowB0 + wn2 * 64 + nt2 * 16 + lb;
                if (a < NA) atomicAdd((float*)outp + a, s);
            }
        }
    }
}

// ---------------- finish: out = scale[Z]*(out + b3) + shift[Z] ----------------
__global__ void k_finish(float* __restrict__ out, const float* __restrict__ b3,
                         const int* __restrict__ Z, const float* __restrict__ scale,
                         const float* __restrict__ shift) {
    int a = blockIdx.x * blockDim.x + threadIdx.x;
    if (a >= NA) return;
    int z = Z[a];
    out[a] = scale[z] * (out[a] + b3[0]) + shift[z];
}

extern "C" void kernel_launch(void* const* d_in, const int* in_sizes, int n_in,
                              void* d_out, int out_size, void* d_ws, size_t ws_size,
                              hipStream_t stream) {
    const float* R    = (const float*)d_in[0];
    const int*   Z    = (const int*)  d_in[1];
    const int*   idx  = (const int*)  d_in[2];
    const float* Wr   = (const float*)d_in[3];
    const float* w1   = (const float*)d_in[4];
    const float* b1   = (const float*)d_in[5];
    const float* w2   = (const float*)d_in[6];
    const float* b2   = (const float*)d_in[7];
    const float* w3   = (const float*)d_in[8];
    const float* b3   = (const float*)d_in[9];
    const float* scale= (const float*)d_in[10];
    const float* shift= (const float*)d_in[11];
    float* out = (float*)d_out;
    char* ws = (char*)d_ws;

    // workspace layout (bytes)
    int*            gcur   = (int*)  (ws + 0);           // 512
    int*            counts = (int*)  (ws + 512);         // 120000 -> 120576 (padded)
    int*            part   = (int*)  (ws + 120576);      // 118*11520*4 = 5437440 -> 5558016
    int*            plist  = (int*)  (ws + 5558016);     // 30000*128*4 = 15360000 -> 20918016
    float*          MT     = (float*)(ws + 20918016);    // 12000000 -> 32918016
    unsigned short* gmB    = (unsigned short*)(ws + 32918016);  // 23101440 -> 56019456
    unsigned short* w1T    = (unsigned short*)(ws + 56019456);  // 393216 -> 56412672
    unsigned short* w2T    = (unsigned short*)(ws + 56412672);  // 524288 -> 56936960
    unsigned short* h1B    = (unsigned short*)(ws + 56936960);  // 30801920 -> 87738880
    float*          Wpad   = (float*)(ws + 87738880);    // 14161*36*4 = 2039184 -> 89778064
    float*          Rpad   = (float*)(ws + 89778064);    // 480000 -> 90258064

    hipMemsetAsync(gcur, 0, 512, stream);
    hipMemsetAsync(d_out, 0, NA * sizeof(float), stream);   // layer-3 accumulator

    k_part    <<<256, 256, 0, stream>>>(idx, Z, gcur, part);
    k_csr     <<<235, 256, 0, stream>>>(part, gcur, counts, plist);
    k_prep    <<<(PREP_TOT + 255) / 256, 256, 0, stream>>>(Wr, R, w1, w2, Wpad, Rpad, w1T, w2T);
    k_moments <<<(NA * 8 + 255) / 256, 256, 0, stream>>>(Rpad, Z, Wpad, counts, plist, MT);
    k_contract<<<(NA + 63) / 64,       256, 0, stream>>>(MT, gmB);

    k_mfma<KP1, 1><<<dim3(NU / 128, 118), 256, 0, stream>>>(gmB, w1T, b1, nullptr, (void*)h1B);
    k_mfma<NU,  2><<<dim3(NU / 128, 118), 256, 0, stream>>>(w2T, h1B, b2, w3, (void*)out);

    k_finish<<<(NA + 255) / 256, 256, 0, stream>>>(out, b3, Z, scale, shift);
}